// Round 11
// baseline (247.737 us; speedup 1.0000x reference)
//
#include <hip/hip_runtime.h>

// Problem constants: B=1, N=256, C=128, H=4, D=32
#define N 256
#define C 128
#define H 4
#define D 32
#define LN_EPS 1e-5f
#define INFB 1e9f
#define SCALE 0.17677669529663687f  // 1/sqrt(32)

typedef __bf16 bf16x8 __attribute__((ext_vector_type(8)));
typedef __bf16 bf16x4 __attribute__((ext_vector_type(4)));
typedef __bf16 bf16x2 __attribute__((ext_vector_type(2)));
typedef _Float16 halfx8 __attribute__((ext_vector_type(8)));
typedef float floatx4 __attribute__((ext_vector_type(4)));

__device__ __forceinline__ floatx4 mfma16(bf16x8 a, bf16x8 b, floatx4 c) {
    return __builtin_amdgcn_mfma_f32_16x16x32_bf16(a, b, c, 0, 0, 0);
}
__device__ __forceinline__ floatx4 mfma16h(halfx8 a, halfx8 b, floatx4 c) {
    return __builtin_amdgcn_mfma_f32_16x16x32_f16(a, b, c, 0, 0, 0);
}

// VALU-pipe lane exchange via DPP (NOT ds_bpermute — keeps the DS pipe free).
// 16-lane reduction tree: xor1 (quad_perm 0xB1), xor2 (quad_perm 0x4E),
// half-mirror 0x141 (merges 4-groups within 8), mirror 0x140 (merges 8s).
#define DPPF(x, ctrl) __builtin_bit_cast(float, \
    __builtin_amdgcn_update_dpp(__builtin_bit_cast(int, (x)), \
        __builtin_bit_cast(int, (x)), (ctrl), 0xF, 0xF, false))

// ---------------------------------------------------------------------------
// K0: weight prep. mats 0..3: wTg[mat][n][c] = (bf16) w[c][n] (transposed).
// mat 4: woh[c][k] = (fp16) wo[c][k] (plain convert, layout kept k-major).
// ---------------------------------------------------------------------------
__global__ __launch_bounds__(256) void wt_kernel(
    const float* __restrict__ wq, const float* __restrict__ wk,
    const float* __restrict__ wv, const float* __restrict__ wg,
    const float* __restrict__ wo, __bf16* __restrict__ wTg,
    _Float16* __restrict__ woh)
{
    const int mat = blockIdx.x >> 3, seg = blockIdx.x & 7;
    if (mat == 4) {
        #pragma unroll
        for (int rep = 0; rep < 8; ++rep) {
            const int idx = seg * 2048 + rep * 256 + threadIdx.x;
            woh[idx] = (_Float16)wo[idx];
        }
        return;
    }
    const float* __restrict__ ws_ = (mat == 0) ? wq : (mat == 1) ? wk
                                  : (mat == 2) ? wv : wg;
    #pragma unroll
    for (int rep = 0; rep < 8; ++rep) {
        const int idx = seg * 2048 + rep * 256 + threadIdx.x;
        const int n = idx >> 7, c = idx & 127;
        wTg[mat * 16384 + n * 128 + c] = (__bf16)ws_[c * 128 + n];
    }
}

// ---------------------------------------------------------------------------
// K1: transpose + LayerNorm -> xn bf16, plus tri-bias (PRE-PERMUTED tbp).
// 32 lanes per row: float4 loads, shfl depth 5, 2 rows/wave, grid 8192.
// Row r = a*256+b holds LN(x[b,a,:]); tbp layout (HW-validated R4):
// value (h,j=a,k=b) -> tbp[((h*16+jb)*64+lnA)*64+slot],
// jb=a>>4, lnA=(b&15)|(((a&15)>>2)<<4), slot=((b>>4)<<2)|(a&3).
// ---------------------------------------------------------------------------
__global__ __launch_bounds__(256) void ln_kernel(
    const float* __restrict__ x, const float* __restrict__ lnw,
    const float* __restrict__ lnb, const float* __restrict__ wbias,
    __bf16* __restrict__ xn, float* __restrict__ tbp)
{
    const int t = threadIdx.x;
    const int wv = t >> 6, half = (t >> 5) & 1, lane = t & 31;
    const int r = blockIdx.x * 8 + wv * 2 + half;
    const int a = r >> 8, b = r & 255;   // tb value for (h, j=a, k=b)

    const float4 v = *(const float4*)&x[((size_t)b * N + a) * C + lane * 4];
    float s  = v.x + v.y + v.z + v.w;
    float ss = v.x*v.x + v.y*v.y + v.z*v.z + v.w*v.w;
    #pragma unroll
    for (int o = 16; o; o >>= 1) {
        s  += __shfl_xor(s,  o);
        ss += __shfl_xor(ss, o);
    }
    const float mu  = s * (1.0f / 128.0f);
    const float var = ss * (1.0f / 128.0f) - mu * mu;
    const float rs  = rsqrtf(var + LN_EPS);

    const float4 lw = *(const float4*)&lnw[lane * 4];
    const float4 lb = *(const float4*)&lnb[lane * 4];
    const float y0 = (v.x - mu) * rs * lw.x + lb.x;
    const float y1 = (v.y - mu) * rs * lw.y + lb.y;
    const float y2 = (v.z - mu) * rs * lw.z + lb.z;
    const float y3 = (v.w - mu) * rs * lw.w + lb.w;

    bf16x4 xo;
    xo[0] = (__bf16)y0; xo[1] = (__bf16)y1;
    xo[2] = (__bf16)y2; xo[3] = (__bf16)y3;
    *(bf16x4*)&xn[(size_t)r * C + lane * 4] = xo;

    // permuted tb address components for (j=a, k=b)
    const int jb   = a >> 4;                             // 16-row j-tile
    const int lnA  = (b & 15) | (((a & 15) >> 2) << 4);  // attn lane
    const int slot = ((b >> 4) << 2) | (a & 3);          // kt*4 + r
    #pragma unroll
    for (int hh = 0; hh < H; ++hh) {
        const float4 wb4 = *(const float4*)&wbias[hh * C + lane * 4];
        float tv = y0 * wb4.x + y1 * wb4.y + y2 * wb4.z + y3 * wb4.w;
        #pragma unroll
        for (int o = 16; o; o >>= 1) tv += __shfl_xor(tv, o);
        if (lane == 0)
            tbp[(size_t)(((hh * 16 + jb) * 64 + lnA) * 64 + slot)] = tv;
    }
}

// ---------------------------------------------------------------------------
// K2: projection GEMM [65536x128]x[128x128] per mat (Q,K,V,G). 4 waves in
// 2x2 64x64 tiles; C-tiles round-trip wave-private LDS so global writes are
// 4KB-contiguous. Outputs [i*4+h][row][32] bf16; Q pre-scaled.
// ---------------------------------------------------------------------------
__global__ __launch_bounds__(256, 3) void proj_kernel(
    const __bf16* __restrict__ xn, const __bf16* __restrict__ wTg,
    __bf16* __restrict__ qbuf, __bf16* __restrict__ kbuf,
    __bf16* __restrict__ vbuf, __bf16* __restrict__ gbuf)
{
    __shared__ __bf16 Cs[4][64 * 72];

    const int mat = blockIdx.y;
    const int t = threadIdx.x, w = t >> 6, lane = t & 63;
    const int ln16 = lane & 15, quad = lane >> 4;
    const int wr = w >> 1, wc = w & 1;
    const int m_base = blockIdx.x * 128 + wr * 64;
    const int n_base = wc * 64;
    const __bf16* __restrict__ wT = wTg + mat * 16384;

    floatx4 Cf[4][4];
    const floatx4 z4 = {0.f, 0.f, 0.f, 0.f};
    #pragma unroll
    for (int mt = 0; mt < 4; ++mt)
        #pragma unroll
        for (int nt = 0; nt < 4; ++nt) Cf[mt][nt] = z4;

    #pragma unroll
    for (int ks = 0; ks < 4; ++ks) {
        bf16x8 Af[4], Bf[4];
        #pragma unroll
        for (int mt = 0; mt < 4; ++mt)
            Af[mt] = *(const bf16x8*)&xn[(size_t)(m_base + mt*16 + ln16) * 128 + ks*32 + quad*8];
        #pragma unroll
        for (int nt = 0; nt < 4; ++nt)
            Bf[nt] = *(const bf16x8*)&wT[(n_base + nt*16 + ln16) * 128 + ks*32 + quad*8];
        #pragma unroll
        for (int mt = 0; mt < 4; ++mt)
            #pragma unroll
            for (int nt = 0; nt < 4; ++nt)
                Cf[mt][nt] = mfma16(Af[mt], Bf[nt], Cf[mt][nt]);
    }

    const float scl = (mat == 0) ? SCALE : 1.0f;
    __bf16* __restrict__ Cw = &Cs[w][0];
    #pragma unroll
    for (int mt = 0; mt < 4; ++mt)
        #pragma unroll
        for (int nt = 0; nt < 4; ++nt)
            #pragma unroll
            for (int r = 0; r < 4; ++r)
                Cw[(mt*16 + quad*4 + r) * 72 + nt*16 + ln16] =
                    (__bf16)(Cf[mt][nt][r] * scl);

    __bf16* __restrict__ dst = (mat == 0) ? qbuf : (mat == 1) ? kbuf
                             : (mat == 2) ? vbuf : gbuf;
    const int m = m_base + lane;
    const int i = m >> 8, jk = m & 255;
    #pragma unroll
    for (int hf = 0; hf < 2; ++hf) {
        const int hh = wc * 2 + hf;
        __bf16* __restrict__ drow = dst + (((size_t)i*4 + hh)*256 + jk)*32;
        #pragma unroll
        for (int u = 0; u < 4; ++u)
            *(bf16x8*)&drow[u*8] = *(const bf16x8*)&Cw[lane*72 + hf*32 + u*8];
    }
}

// ---------------------------------------------------------------------------
// K3: MFMA attention, one (i,h) per block. R10 post-mortem: residency 2/3/4
// blocks/CU all measure identical (65.4-65.7 us) — the kernel is bound by
// the per-CU DS pipe, which every wave shares (and __shfl lowers to
// ds_bpermute, i.e. DS too). This round CUTS DS OPS, paying registers:
//  - V fragments hoisted to regs once per block (16 b128 reads, was 64
//    across the 4 jt). +64 VGPR — occupancy drop to 2 blocks/CU is FREE
//    per the R8/R9/R10 equivalence.
//  - softmax reductions on the VALU pipe via DPP (quad_perm xor1/xor2 +
//    half-mirror + mirror — each step pairs disjoint halves, valid for
//    max/sum trees). Removes 128 ds_bpermute per wave per block.
// Bias folded into MFMA C-operand (R6 spill lesson); K LDS-staged (R3);
// Ks XOR-swizzled (R10); launch bounds (256,2) — forced caps collapse
// regalloc (R5). Rule #20: all S[]/Vf[] indices compile-time constant.
// ---------------------------------------------------------------------------
__global__ __launch_bounds__(256, 2) void attn_kernel(
    const float* __restrict__ tbp, const float* __restrict__ mask,
    const float* __restrict__ bg,
    const __bf16* __restrict__ qbuf, const __bf16* __restrict__ kbuf,
    const __bf16* __restrict__ vbuf, const __bf16* __restrict__ gbuf,
    _Float16* __restrict__ ogh)
{
    const int bid = blockIdx.x;
    const int i = bid & 255, h = bid >> 8;
    const int t = threadIdx.x, w = t >> 6, lane = t & 63;
    const int ln16 = lane & 15, quad = lane >> 4;

    __shared__ __align__(16) __bf16 Ks[256 * 32];      // 16384 B (swizzled)
    __shared__ __align__(16) __bf16 VT[32 * 264];      // 16896 B
    __shared__ __align__(16) __bf16 Pw[4][16 * 40];    //  5120 B
    __shared__ float mb[256];                          //  1024 B

    const size_t hb = (size_t)i * 4 + h;
    const __bf16* __restrict__ qb = qbuf + hb * 8192;
    const __bf16* __restrict__ kb = kbuf + hb * 8192;
    const __bf16* __restrict__ vb = vbuf + hb * 8192;
    const __bf16* __restrict__ gb = gbuf + hb * 8192;

    // K staging: swizzled 16B-block placement
    {
        const int xt = (t & 3) ^ ((t >> 2) & 3);
        #pragma unroll
        for (int u = 0; u < 4; ++u)
            *(bf16x8*)&Ks[t * 32 + ((u ^ xt) * 8)] = *(const bf16x8*)&kb[t * 32 + u * 8];
    }
    #pragma unroll
    for (int u = 0; u < 4; ++u) {
        const bf16x8 vv = *(const bf16x8*)&vb[t * 32 + u * 8];
        #pragma unroll
        for (int e = 0; e < 8; ++e) VT[(u*8 + e) * 264 + t] = vv[e];
    }
    mb[t] = INFB * (mask[(size_t)t * N + i] - 1.0f);
    __syncthreads();

    const float bg0 = bg[h*32 + ln16], bg1 = bg[h*32 + 16 + ln16];

    float mbv[16];
    #pragma unroll
    for (int kt = 0; kt < 16; ++kt) mbv[kt] = mb[kt*16 + ln16];

    // V fragments -> registers once per block (jt-invariant; 64 VGPRs)
    bf16x8 Vf0[8], Vf1[8];
    #pragma unroll
    for (int ks = 0; ks < 8; ++ks) {
        Vf0[ks] = *(const bf16x8*)&VT[ln16*264 + ks*32 + quad*8];
        Vf1[ks] = *(const bf16x8*)&VT[(16 + ln16)*264 + ks*32 + quad*8];
    }

    // per-lane constant swizzled K-block offset
    const int kq = ((quad ^ ((ln16 & 3) ^ ((ln16 >> 2) & 3))) * 8);

    __bf16* __restrict__ Pww = &Pw[w][0];
    const floatx4 z4 = {0.f, 0.f, 0.f, 0.f};
    _Float16* __restrict__ ogb = ogh + ((size_t)h * 256 + i) * 8192;

    #pragma unroll 1
    for (int jt = 0; jt < 4; ++jt) {
        const int jrow0 = w*64 + jt*16;
        // per-lane contiguous 256B slab of pre-permuted tri-bias
        const float* __restrict__ tbl =
            tbp + ((size_t)((h*16 + (w*4 + jt))*64 + lane) << 6);
        const bf16x8 Qf = *(const bf16x8*)&qb[(jrow0 + ln16)*32 + quad*8];

        // ---- scores with bias folded into the MFMA C-operand ----
        floatx4 S[16];
        #pragma unroll
        for (int kt = 0; kt < 16; ++kt) {
            const float4 tb4 = *(const float4*)&tbl[kt*4];
            const float mbk = mbv[kt];
            floatx4 c;
            c[0] = mbk + tb4.x;
            c[1] = mbk + tb4.y;
            c[2] = mbk + tb4.z;
            c[3] = mbk + tb4.w;
            const bf16x8 Kf = *(const bf16x8*)&Ks[(kt*16 + ln16)*32 + kq];
            S[kt] = mfma16(Qf, Kf, c);
        }

        // ---- full-row softmax: 16-lane reduce entirely on VALU (DPP) ----
        float mrow[4], l[4];
        #pragma unroll
        for (int r = 0; r < 4; ++r) {
            float mx = S[0][r];
            #pragma unroll
            for (int kt = 1; kt < 16; ++kt) mx = fmaxf(mx, S[kt][r]);
            mx = fmaxf(mx, DPPF(mx, 0xB1));   // quad_perm xor1
            mx = fmaxf(mx, DPPF(mx, 0x4E));   // quad_perm xor2
            mx = fmaxf(mx, DPPF(mx, 0x141));  // row_half_mirror (merge 4s)
            mx = fmaxf(mx, DPPF(mx, 0x140));  // row_mirror (merge 8s)
            mrow[r] = mx; l[r] = 0.f;
        }
        #pragma unroll
        for (int kt = 0; kt < 16; ++kt)
            #pragma unroll
            for (int r = 0; r < 4; ++r) {
                const float p = __expf(S[kt][r] - mrow[r]);
                S[kt][r] = p; l[r] += p;
            }
        #pragma unroll
        for (int r = 0; r < 4; ++r) {
            float lv = l[r];
            lv += DPPF(lv, 0xB1);
            lv += DPPF(lv, 0x4E);
            lv += DPPF(lv, 0x141);
            lv += DPPF(lv, 0x140);
            l[r] = lv;
        }

        // ---- PV in 8 key-chunks of 32: P-chunk -> LDS, V from registers ----
        floatx4 O0 = z4, O1 = z4;
        #pragma unroll
        for (int ch = 0; ch < 8; ++ch) {
            #pragma unroll
            for (int kk = 0; kk < 2; ++kk) {
                const int kt = ch*2 + kk;
                #pragma unroll
                for (int r = 0; r < 4; ++r)
                    Pww[(quad*4 + r)*40 + kk*16 + ln16] = (__bf16)S[kt][r];
            }
            const bf16x8 Af = *(const bf16x8*)&Pww[ln16*40 + quad*8];
            O0 = mfma16(Af, Vf0[ch], O0);
            O1 = mfma16(Af, Vf1[ch], O1);
        }

        // ---- normalize+gate -> fp16 repack in wave-private LDS ----
        _Float16* Po = (_Float16*)Pww;
        #pragma unroll
        for (int r = 0; r < 4; ++r) {
            const float inv = 1.0f / l[r];
            const int jrow = jrow0 + quad*4 + r;
            const float g0 = (float)gb[jrow*32 + ln16];
            const float g1 = (float)gb[jrow*32 + 16 + ln16];
            const float gate0 = 1.0f / (1.0f + __expf(-(g0 + bg0)));
            const float gate1 = 1.0f / (1.0f + __expf(-(g1 + bg1)));
            Po[(quad*4 + r)*40 + ln16]      = (_Float16)(O0[r] * inv * gate0);
            Po[(quad*4 + r)*40 + 16 + ln16] = (_Float16)(O1[r] * inv * gate1);
        }
        // contiguous 1KB-per-wave store (in-order DS pipe, wave-private)
        {
            const int rr = lane >> 2, cc = lane & 3;
            const halfx8 ov = *(const halfx8*)&Po[rr*40 + cc*8];
            *(halfx8*)&ogb[(size_t)(jrow0 + rr)*32 + cc*8] = ov;
        }
    }
}

// ---------------------------------------------------------------------------
// K4: output projection as f16 MFMA GEMM: out[(j*256+i)*128 + c] =
// sum_k og[(i*256+j), k] * woh[c, k] + bo[c], k = h*32+d over 4 head-slices.
// No LDS; A from og fp16 (coalesced), B from woh (L2-resident).
// ---------------------------------------------------------------------------
__global__ __launch_bounds__(256, 4) void outproj_kernel(
    const _Float16* __restrict__ og, const _Float16* __restrict__ woh,
    const float* __restrict__ bo, float* __restrict__ out)
{
    const int t = threadIdx.x, w = t >> 6, lane = t & 63;
    const int ln16 = lane & 15, quad = lane >> 4;
    const int wr = w >> 1, wc = w & 1;
    const int m_base = blockIdx.x * 128 + wr * 64;
    const int n_base = wc * 64;

    floatx4 Cf[4][4];
    const floatx4 z4 = {0.f, 0.f, 0.f, 0.f};
    #pragma unroll
    for (int mt = 0; mt < 4; ++mt)
        #pragma unroll
        for (int nt = 0; nt < 4; ++nt) Cf[mt][nt] = z4;

    #pragma unroll
    for (int ks = 0; ks < 4; ++ks) {   // ks = head
        halfx8 Af[4], Bf[4];
        #pragma unroll
        for (int mt = 0; mt < 4; ++mt)
            Af[mt] = *(const halfx8*)&og[(size_t)ks*2097152 + (size_t)(m_base + mt*16 + ln16)*32 + quad*8];
        #pragma unroll
        for (int nt = 0; nt < 4; ++nt)
            Bf[nt] = *(const halfx8*)&woh[(n_base + nt*16 + ln16)*128 + ks*32 + quad*8];
        #pragma unroll
        for (int mt = 0; mt < 4; ++mt)
            #pragma unroll
            for (int nt = 0; nt < 4; ++nt)
                Cf[mt][nt] = mfma16h(Af[mt], Bf[nt], Cf[mt][nt]);
    }

    float bov[4];
    #pragma unroll
    for (int nt = 0; nt < 4; ++nt) bov[nt] = bo[n_base + nt*16 + ln16];

    #pragma unroll
    for (int mt = 0; mt < 4; ++mt)
        #pragma unroll
        for (int r = 0; r < 4; ++r) {
            const int m = m_base + mt*16 + quad*4 + r;
            const size_t orow = (size_t)(m & 255) * 256 + (m >> 8);  // (j,i)
            #pragma unroll
            for (int nt = 0; nt < 4; ++nt)
                out[orow*128 + n_base + nt*16 + ln16] = Cf[mt][nt][r] + bov[nt];
        }
}

// ---------------------------------------------------------------------------
extern "C" void kernel_launch(void* const* d_in, const int* in_sizes, int n_in,
                              void* d_out, int out_size, void* d_ws, size_t ws_size,
                              hipStream_t stream) {
    const float* x     = (const float*)d_in[0];
    const float* mask  = (const float*)d_in[1];
    const float* lnw   = (const float*)d_in[2];
    const float* lnb   = (const float*)d_in[3];
    const float* wbias = (const float*)d_in[4];
    const float* wq    = (const float*)d_in[5];
    const float* wk    = (const float*)d_in[6];
    const float* wv    = (const float*)d_in[7];
    const float* wg    = (const float*)d_in[8];
    const float* bg    = (const float*)d_in[9];
    const float* wo    = (const float*)d_in[10];
    const float* bo    = (const float*)d_in[11];
    float* out = (float*)d_out;

    char* wsb = (char*)d_ws;
    __bf16*    xn   = (__bf16*)   (wsb);              // 16.78 MB
    float*     tbp  = (float*)    (wsb + 16777216);   //  1.05 MB (permuted)
    __bf16*    wTg  = (__bf16*)   (wsb + 17825792);   //  0.13 MB
    _Float16*  woh  = (_Float16*) (wsb + 17956864);   //  0.03 MB
    __bf16*    qbuf = (__bf16*)   (wsb + 17989632);   // 16.78 MB
    __bf16*    kbuf = (__bf16*)   (wsb + 34766848);   // 16.78 MB
    __bf16*    vbuf = (__bf16*)   (wsb + 51544064);   // 16.78 MB
    __bf16*    gbuf = (__bf16*)   (wsb + 68321280);   // 16.78 MB
    _Float16*  ogh  = (_Float16*) (wsb + 85098496);   // 16.78 MB (total ~102 MB)

    wt_kernel<<<40, 256, 0, stream>>>(wq, wk, wv, wg, wo, wTg, woh);
    ln_kernel<<<8192, 256, 0, stream>>>(x, lnw, lnb, wbias, xn, tbp);
    proj_kernel<<<dim3(512, 4), 256, 0, stream>>>(xn, wTg, qbuf, kbuf, vbuf, gbuf);
    attn_kernel<<<1024, 256, 0, stream>>>(tbp, mask, bg, qbuf, kbuf, vbuf, gbuf, ogh);
    outproj_kernel<<<512, 256, 0, stream>>>(ogh, woh, bo, out);
}

// Round 12
// 243.858 us; speedup vs baseline: 1.0159x; 1.0159x over previous
//
#include <hip/hip_runtime.h>

// Problem constants: B=1, N=256, C=128, H=4, D=32
#define N 256
#define C 128
#define H 4
#define D 32
#define LN_EPS 1e-5f
#define INFB 1e9f
#define SCALE 0.17677669529663687f  // 1/sqrt(32)

typedef __bf16 bf16x8 __attribute__((ext_vector_type(8)));
typedef __bf16 bf16x4 __attribute__((ext_vector_type(4)));
typedef __bf16 bf16x2 __attribute__((ext_vector_type(2)));
typedef _Float16 halfx8 __attribute__((ext_vector_type(8)));
typedef float floatx4 __attribute__((ext_vector_type(4)));

__device__ __forceinline__ floatx4 mfma16(bf16x8 a, bf16x8 b, floatx4 c) {
    return __builtin_amdgcn_mfma_f32_16x16x32_bf16(a, b, c, 0, 0, 0);
}
__device__ __forceinline__ floatx4 mfma16h(halfx8 a, halfx8 b, floatx4 c) {
    return __builtin_amdgcn_mfma_f32_16x16x32_f16(a, b, c, 0, 0, 0);
}

// ---------------------------------------------------------------------------
// K0: weight prep. mats 0..3: wTg[mat][n][c] = (bf16) w[c][n] (transposed).
// mat 4: woh[c][k] = (fp16) wo[c][k] (plain convert, layout kept k-major).
// ---------------------------------------------------------------------------
__global__ __launch_bounds__(256) void wt_kernel(
    const float* __restrict__ wq, const float* __restrict__ wk,
    const float* __restrict__ wv, const float* __restrict__ wg,
    const float* __restrict__ wo, __bf16* __restrict__ wTg,
    _Float16* __restrict__ woh)
{
    const int mat = blockIdx.x >> 3, seg = blockIdx.x & 7;
    if (mat == 4) {
        #pragma unroll
        for (int rep = 0; rep < 8; ++rep) {
            const int idx = seg * 2048 + rep * 256 + threadIdx.x;
            woh[idx] = (_Float16)wo[idx];
        }
        return;
    }
    const float* __restrict__ ws_ = (mat == 0) ? wq : (mat == 1) ? wk
                                  : (mat == 2) ? wv : wg;
    #pragma unroll
    for (int rep = 0; rep < 8; ++rep) {
        const int idx = seg * 2048 + rep * 256 + threadIdx.x;
        const int n = idx >> 7, c = idx & 127;
        wTg[mat * 16384 + n * 128 + c] = (__bf16)ws_[c * 128 + n];
    }
}

// ---------------------------------------------------------------------------
// K1: transpose + LayerNorm -> xn bf16, plus tri-bias (PRE-PERMUTED tbp).
// 32 lanes per row: float4 loads, shfl depth 5, 2 rows/wave, grid 8192.
// Row r = a*256+b holds LN(x[b,a,:]); tbp layout (HW-validated R4):
// value (h,j=a,k=b) -> tbp[((h*16+jb)*64+lnA)*64+slot],
// jb=a>>4, lnA=(b&15)|(((a&15)>>2)<<4), slot=((b>>4)<<2)|(a&3).
// ---------------------------------------------------------------------------
__global__ __launch_bounds__(256) void ln_kernel(
    const float* __restrict__ x, const float* __restrict__ lnw,
    const float* __restrict__ lnb, const float* __restrict__ wbias,
    __bf16* __restrict__ xn, float* __restrict__ tbp)
{
    const int t = threadIdx.x;
    const int wv = t >> 6, half = (t >> 5) & 1, lane = t & 31;
    const int r = blockIdx.x * 8 + wv * 2 + half;
    const int a = r >> 8, b = r & 255;   // tb value for (h, j=a, k=b)

    const float4 v = *(const float4*)&x[((size_t)b * N + a) * C + lane * 4];
    float s  = v.x + v.y + v.z + v.w;
    float ss = v.x*v.x + v.y*v.y + v.z*v.z + v.w*v.w;
    #pragma unroll
    for (int o = 16; o; o >>= 1) {
        s  += __shfl_xor(s,  o);
        ss += __shfl_xor(ss, o);
    }
    const float mu  = s * (1.0f / 128.0f);
    const float var = ss * (1.0f / 128.0f) - mu * mu;
    const float rs  = rsqrtf(var + LN_EPS);

    const float4 lw = *(const float4*)&lnw[lane * 4];
    const float4 lb = *(const float4*)&lnb[lane * 4];
    const float y0 = (v.x - mu) * rs * lw.x + lb.x;
    const float y1 = (v.y - mu) * rs * lw.y + lb.y;
    const float y2 = (v.z - mu) * rs * lw.z + lb.z;
    const float y3 = (v.w - mu) * rs * lw.w + lb.w;

    bf16x4 xo;
    xo[0] = (__bf16)y0; xo[1] = (__bf16)y1;
    xo[2] = (__bf16)y2; xo[3] = (__bf16)y3;
    *(bf16x4*)&xn[(size_t)r * C + lane * 4] = xo;

    // permuted tb address components for (j=a, k=b)
    const int jb   = a >> 4;                             // 16-row j-tile
    const int lnA  = (b & 15) | (((a & 15) >> 2) << 4);  // attn lane
    const int slot = ((b >> 4) << 2) | (a & 3);          // kt*4 + r
    #pragma unroll
    for (int hh = 0; hh < H; ++hh) {
        const float4 wb4 = *(const float4*)&wbias[hh * C + lane * 4];
        float tv = y0 * wb4.x + y1 * wb4.y + y2 * wb4.z + y3 * wb4.w;
        #pragma unroll
        for (int o = 16; o; o >>= 1) tv += __shfl_xor(tv, o);
        if (lane == 0)
            tbp[(size_t)(((hh * 16 + jb) * 64 + lnA) * 64 + slot)] = tv;
    }
}

// ---------------------------------------------------------------------------
// K2: projection GEMM [65536x128]x[128x128] per mat (Q,K,V,G). 4 waves in
// 2x2 64x64 tiles; C-tiles round-trip wave-private LDS so global writes are
// 4KB-contiguous. Outputs [i*4+h][row][32] bf16; Q pre-scaled.
// ---------------------------------------------------------------------------
__global__ __launch_bounds__(256, 3) void proj_kernel(
    const __bf16* __restrict__ xn, const __bf16* __restrict__ wTg,
    __bf16* __restrict__ qbuf, __bf16* __restrict__ kbuf,
    __bf16* __restrict__ vbuf, __bf16* __restrict__ gbuf)
{
    __shared__ __bf16 Cs[4][64 * 72];

    const int mat = blockIdx.y;
    const int t = threadIdx.x, w = t >> 6, lane = t & 63;
    const int ln16 = lane & 15, quad = lane >> 4;
    const int wr = w >> 1, wc = w & 1;
    const int m_base = blockIdx.x * 128 + wr * 64;
    const int n_base = wc * 64;
    const __bf16* __restrict__ wT = wTg + mat * 16384;

    floatx4 Cf[4][4];
    const floatx4 z4 = {0.f, 0.f, 0.f, 0.f};
    #pragma unroll
    for (int mt = 0; mt < 4; ++mt)
        #pragma unroll
        for (int nt = 0; nt < 4; ++nt) Cf[mt][nt] = z4;

    #pragma unroll
    for (int ks = 0; ks < 4; ++ks) {
        bf16x8 Af[4], Bf[4];
        #pragma unroll
        for (int mt = 0; mt < 4; ++mt)
            Af[mt] = *(const bf16x8*)&xn[(size_t)(m_base + mt*16 + ln16) * 128 + ks*32 + quad*8];
        #pragma unroll
        for (int nt = 0; nt < 4; ++nt)
            Bf[nt] = *(const bf16x8*)&wT[(n_base + nt*16 + ln16) * 128 + ks*32 + quad*8];
        #pragma unroll
        for (int mt = 0; mt < 4; ++mt)
            #pragma unroll
            for (int nt = 0; nt < 4; ++nt)
                Cf[mt][nt] = mfma16(Af[mt], Bf[nt], Cf[mt][nt]);
    }

    const float scl = (mat == 0) ? SCALE : 1.0f;
    __bf16* __restrict__ Cw = &Cs[w][0];
    #pragma unroll
    for (int mt = 0; mt < 4; ++mt)
        #pragma unroll
        for (int nt = 0; nt < 4; ++nt)
            #pragma unroll
            for (int r = 0; r < 4; ++r)
                Cw[(mt*16 + quad*4 + r) * 72 + nt*16 + ln16] =
                    (__bf16)(Cf[mt][nt][r] * scl);

    __bf16* __restrict__ dst = (mat == 0) ? qbuf : (mat == 1) ? kbuf
                             : (mat == 2) ? vbuf : gbuf;
    const int m = m_base + lane;
    const int i = m >> 8, jk = m & 255;
    #pragma unroll
    for (int hf = 0; hf < 2; ++hf) {
        const int hh = wc * 2 + hf;
        __bf16* __restrict__ drow = dst + (((size_t)i*4 + hh)*256 + jk)*32;
        #pragma unroll
        for (int u = 0; u < 4; ++u)
            *(bf16x8*)&drow[u*8] = *(const bf16x8*)&Cw[lane*72 + hf*32 + u*8];
    }
}

// ---------------------------------------------------------------------------
// K3: MFMA attention, one (i,h) per block — R10 structure with the block
// split across EIGHT waves (512 threads): each wave owns 2 j-tiles instead
// of 4, HALVING the per-wave serial chain (QK->softmax->PV->epilogue).
// Rationale: R8-R10 showed adding resident BLOCKS does nothing; R11's
// register-paid DS cut spilled (V-hoist +64 VGPR > the ~128 ceiling; WRITE
// 16->57 MB). Chain LENGTH is the one untested knob, and it needs no new
// registers and no data-layout change.
// LDS 44.5 KB (Pw gets 8 wave slots) -> 2 blocks/CU = 16 waves/CU at
// VGPR<=128. Staging re-divided over 512 threads (bit-identical formulas:
// t&3 / (t>>2)&3 ignore bit 8).
// Kept: Ks XOR-swizzle (R10), bias folded into MFMA C (R6/R8), K LDS-staged
// (R3), shfl_xor softmax (R10 form — DPP unattributed under R11's spill).
// Launch bounds (512,2): budget 256 (R5: tighter caps collapse regalloc).
// Rule #20: all S[] indices compile-time constant.
// ---------------------------------------------------------------------------
__global__ __launch_bounds__(512, 2) void attn_kernel(
    const float* __restrict__ tbp, const float* __restrict__ mask,
    const float* __restrict__ bg,
    const __bf16* __restrict__ qbuf, const __bf16* __restrict__ kbuf,
    const __bf16* __restrict__ vbuf, const __bf16* __restrict__ gbuf,
    _Float16* __restrict__ ogh)
{
    const int bid = blockIdx.x;
    const int i = bid & 255, h = bid >> 8;
    const int t = threadIdx.x, w = t >> 6, lane = t & 63;
    const int ln16 = lane & 15, quad = lane >> 4;

    __shared__ __align__(16) __bf16 Ks[256 * 32];      // 16384 B (swizzled)
    __shared__ __align__(16) __bf16 VT[32 * 264];      // 16896 B
    __shared__ __align__(16) __bf16 Pw[8][16 * 40];    // 10240 B
    __shared__ float mb[256];                          //  1024 B
    // total 44544 B -> 2 blocks/CU (16 waves/CU) at VGPR <= 128

    const size_t hb = (size_t)i * 4 + h;
    const __bf16* __restrict__ qb = qbuf + hb * 8192;
    const __bf16* __restrict__ kb = kbuf + hb * 8192;
    const __bf16* __restrict__ vb = vbuf + hb * 8192;
    const __bf16* __restrict__ gb = gbuf + hb * 8192;

    // staging split over 512 threads: row = t&255, u-half = (t>>8)*2
    const int row = t & 255, uh = (t >> 8) << 1;
    {
        const int xt = (row & 3) ^ ((row >> 2) & 3);
        #pragma unroll
        for (int uu = 0; uu < 2; ++uu) {
            const int u = uh + uu;
            *(bf16x8*)&Ks[row * 32 + ((u ^ xt) * 8)] = *(const bf16x8*)&kb[row * 32 + u * 8];
        }
    }
    #pragma unroll
    for (int uu = 0; uu < 2; ++uu) {
        const int u = uh + uu;
        const bf16x8 vv = *(const bf16x8*)&vb[row * 32 + u * 8];
        #pragma unroll
        for (int e = 0; e < 8; ++e) VT[(u*8 + e) * 264 + row] = vv[e];
    }
    if (t < 256) mb[t] = INFB * (mask[(size_t)t * N + i] - 1.0f);
    __syncthreads();

    const float bg0 = bg[h*32 + ln16], bg1 = bg[h*32 + 16 + ln16];

    float mbv[16];
    #pragma unroll
    for (int kt = 0; kt < 16; ++kt) mbv[kt] = mb[kt*16 + ln16];

    // per-lane constant swizzled K-block offset
    const int kq = ((quad ^ ((ln16 & 3) ^ ((ln16 >> 2) & 3))) * 8);

    __bf16* __restrict__ Pww = &Pw[w][0];
    const floatx4 z4 = {0.f, 0.f, 0.f, 0.f};
    _Float16* __restrict__ ogb = ogh + ((size_t)h * 256 + i) * 8192;

    #pragma unroll 1
    for (int jt = 0; jt < 2; ++jt) {
        const int jrow0 = w*32 + jt*16;
        // per-lane contiguous 256B slab of pre-permuted tri-bias
        const float* __restrict__ tbl =
            tbp + ((size_t)((h*16 + (w*2 + jt))*64 + lane) << 6);
        const bf16x8 Qf = *(const bf16x8*)&qb[(jrow0 + ln16)*32 + quad*8];

        // ---- scores with bias folded into the MFMA C-operand ----
        floatx4 S[16];
        #pragma unroll
        for (int kt = 0; kt < 16; ++kt) {
            const float4 tb4 = *(const float4*)&tbl[kt*4];
            const float mbk = mbv[kt];
            floatx4 c;
            c[0] = mbk + tb4.x;
            c[1] = mbk + tb4.y;
            c[2] = mbk + tb4.z;
            c[3] = mbk + tb4.w;
            const bf16x8 Kf = *(const bf16x8*)&Ks[(kt*16 + ln16)*32 + kq];
            S[kt] = mfma16(Qf, Kf, c);
        }

        // ---- full-row softmax (16-lane shfl reduce) ----
        float mrow[4], l[4];
        #pragma unroll
        for (int r = 0; r < 4; ++r) {
            float mx = S[0][r];
            #pragma unroll
            for (int kt = 1; kt < 16; ++kt) mx = fmaxf(mx, S[kt][r]);
            #pragma unroll
            for (int off = 1; off < 16; off <<= 1) mx = fmaxf(mx, __shfl_xor(mx, off));
            mrow[r] = mx; l[r] = 0.f;
        }
        #pragma unroll
        for (int kt = 0; kt < 16; ++kt)
            #pragma unroll
            for (int r = 0; r < 4; ++r) {
                const float p = __expf(S[kt][r] - mrow[r]);
                S[kt][r] = p; l[r] += p;
            }
        #pragma unroll
        for (int r = 0; r < 4; ++r)
            #pragma unroll
            for (int off = 1; off < 16; off <<= 1) l[r] += __shfl_xor(l[r], off);

        // ---- PV in 8 key-chunks of 32: P-chunk -> LDS, 1 MFMA pair each ----
        floatx4 O0 = z4, O1 = z4;
        #pragma unroll
        for (int ch = 0; ch < 8; ++ch) {
            #pragma unroll
            for (int kk = 0; kk < 2; ++kk) {
                const int kt = ch*2 + kk;
                #pragma unroll
                for (int r = 0; r < 4; ++r)
                    Pww[(quad*4 + r)*40 + kk*16 + ln16] = (__bf16)S[kt][r];
            }
            const bf16x8 Af = *(const bf16x8*)&Pww[ln16*40 + quad*8];
            const bf16x8 V0 = *(const bf16x8*)&VT[ln16*264 + ch*32 + quad*8];
            const bf16x8 V1 = *(const bf16x8*)&VT[(16 + ln16)*264 + ch*32 + quad*8];
            O0 = mfma16(Af, V0, O0);
            O1 = mfma16(Af, V1, O1);
        }

        // ---- normalize+gate -> fp16 repack in wave-private LDS ----
        _Float16* Po = (_Float16*)Pww;
        #pragma unroll
        for (int r = 0; r < 4; ++r) {
            const float inv = 1.0f / l[r];
            const int jrow = jrow0 + quad*4 + r;
            const float g0 = (float)gb[jrow*32 + ln16];
            const float g1 = (float)gb[jrow*32 + 16 + ln16];
            const float gate0 = 1.0f / (1.0f + __expf(-(g0 + bg0)));
            const float gate1 = 1.0f / (1.0f + __expf(-(g1 + bg1)));
            Po[(quad*4 + r)*40 + ln16]      = (_Float16)(O0[r] * inv * gate0);
            Po[(quad*4 + r)*40 + 16 + ln16] = (_Float16)(O1[r] * inv * gate1);
        }
        // contiguous 1KB-per-wave store (in-order DS pipe, wave-private)
        {
            const int rr = lane >> 2, cc = lane & 3;
            const halfx8 ov = *(const halfx8*)&Po[rr*40 + cc*8];
            *(halfx8*)&ogb[(size_t)(jrow0 + rr)*32 + cc*8] = ov;
        }
    }
}

// ---------------------------------------------------------------------------
// K4: output projection as f16 MFMA GEMM: out[(j*256+i)*128 + c] =
// sum_k og[(i*256+j), k] * woh[c, k] + bo[c], k = h*32+d over 4 head-slices.
// No LDS; A from og fp16 (coalesced), B from woh (L2-resident).
// ---------------------------------------------------------------------------
__global__ __launch_bounds__(256, 4) void outproj_kernel(
    const _Float16* __restrict__ og, const _Float16* __restrict__ woh,
    const float* __restrict__ bo, float* __restrict__ out)
{
    const int t = threadIdx.x, w = t >> 6, lane = t & 63;
    const int ln16 = lane & 15, quad = lane >> 4;
    const int wr = w >> 1, wc = w & 1;
    const int m_base = blockIdx.x * 128 + wr * 64;
    const int n_base = wc * 64;

    floatx4 Cf[4][4];
    const floatx4 z4 = {0.f, 0.f, 0.f, 0.f};
    #pragma unroll
    for (int mt = 0; mt < 4; ++mt)
        #pragma unroll
        for (int nt = 0; nt < 4; ++nt) Cf[mt][nt] = z4;

    #pragma unroll
    for (int ks = 0; ks < 4; ++ks) {   // ks = head
        halfx8 Af[4], Bf[4];
        #pragma unroll
        for (int mt = 0; mt < 4; ++mt)
            Af[mt] = *(const halfx8*)&og[(size_t)ks*2097152 + (size_t)(m_base + mt*16 + ln16)*32 + quad*8];
        #pragma unroll
        for (int nt = 0; nt < 4; ++nt)
            Bf[nt] = *(const halfx8*)&woh[(n_base + nt*16 + ln16)*128 + ks*32 + quad*8];
        #pragma unroll
        for (int mt = 0; mt < 4; ++mt)
            #pragma unroll
            for (int nt = 0; nt < 4; ++nt)
                Cf[mt][nt] = mfma16h(Af[mt], Bf[nt], Cf[mt][nt]);
    }

    float bov[4];
    #pragma unroll
    for (int nt = 0; nt < 4; ++nt) bov[nt] = bo[n_base + nt*16 + ln16];

    #pragma unroll
    for (int mt = 0; mt < 4; ++mt)
        #pragma unroll
        for (int r = 0; r < 4; ++r) {
            const int m = m_base + mt*16 + quad*4 + r;
            const size_t orow = (size_t)(m & 255) * 256 + (m >> 8);  // (j,i)
            #pragma unroll
            for (int nt = 0; nt < 4; ++nt)
                out[orow*128 + n_base + nt*16 + ln16] = Cf[mt][nt][r] + bov[nt];
        }
}

// ---------------------------------------------------------------------------
extern "C" void kernel_launch(void* const* d_in, const int* in_sizes, int n_in,
                              void* d_out, int out_size, void* d_ws, size_t ws_size,
                              hipStream_t stream) {
    const float* x     = (const float*)d_in[0];
    const float* mask  = (const float*)d_in[1];
    const float* lnw   = (const float*)d_in[2];
    const float* lnb   = (const float*)d_in[3];
    const float* wbias = (const float*)d_in[4];
    const float* wq    = (const float*)d_in[5];
    const float* wk    = (const float*)d_in[6];
    const float* wv    = (const float*)d_in[7];
    const float* wg    = (const float*)d_in[8];
    const float* bg    = (const float*)d_in[9];
    const float* wo    = (const float*)d_in[10];
    const float* bo    = (const float*)d_in[11];
    float* out = (float*)d_out;

    char* wsb = (char*)d_ws;
    __bf16*    xn   = (__bf16*)   (wsb);              // 16.78 MB
    float*     tbp  = (float*)    (wsb + 16777216);   //  1.05 MB (permuted)
    __bf16*    wTg  = (__bf16*)   (wsb + 17825792);   //  0.13 MB
    _Float16*  woh  = (_Float16*) (wsb + 17956864);   //  0.03 MB
    __bf16*    qbuf = (__bf16*)   (wsb + 17989632);   // 16.78 MB
    __bf16*    kbuf = (__bf16*)   (wsb + 34766848);   // 16.78 MB
    __bf16*    vbuf = (__bf16*)   (wsb + 51544064);   // 16.78 MB
    __bf16*    gbuf = (__bf16*)   (wsb + 68321280);   // 16.78 MB
    _Float16*  ogh  = (_Float16*) (wsb + 85098496);   // 16.78 MB (total ~102 MB)

    wt_kernel<<<40, 256, 0, stream>>>(wq, wk, wv, wg, wo, wTg, woh);
    ln_kernel<<<8192, 256, 0, stream>>>(x, lnw, lnb, wbias, xn, tbp);
    proj_kernel<<<dim3(512, 4), 256, 0, stream>>>(xn, wTg, qbuf, kbuf, vbuf, gbuf);
    attn_kernel<<<1024, 512, 0, stream>>>(tbp, mask, bg, qbuf, kbuf, vbuf, gbuf, ogh);
    outproj_kernel<<<512, 256, 0, stream>>>(ogh, woh, bo, out);
}

// Round 13
// 239.197 us; speedup vs baseline: 1.0357x; 1.0195x over previous
//
#include <hip/hip_runtime.h>

// Problem constants: B=1, N=256, C=128, H=4, D=32
#define N 256
#define C 128
#define H 4
#define D 32
#define LN_EPS 1e-5f
#define INFB 1e9f
#define SCALE 0.17677669529663687f  // 1/sqrt(32)

typedef __bf16 bf16x8 __attribute__((ext_vector_type(8)));
typedef __bf16 bf16x4 __attribute__((ext_vector_type(4)));
typedef __bf16 bf16x2 __attribute__((ext_vector_type(2)));
typedef _Float16 halfx8 __attribute__((ext_vector_type(8)));
typedef float floatx4 __attribute__((ext_vector_type(4)));

__device__ __forceinline__ floatx4 mfma16(bf16x8 a, bf16x8 b, floatx4 c) {
    return __builtin_amdgcn_mfma_f32_16x16x32_bf16(a, b, c, 0, 0, 0);
}
__device__ __forceinline__ floatx4 mfma16h(halfx8 a, halfx8 b, floatx4 c) {
    return __builtin_amdgcn_mfma_f32_16x16x32_f16(a, b, c, 0, 0, 0);
}

// ---------------------------------------------------------------------------
// K0: weight prep. mats 0..3: wTg[mat][n][c] = (bf16) w[c][n] (transposed).
// mat 4: woh[c][k] = (fp16) wo[c][k] (plain convert, layout kept k-major).
// ---------------------------------------------------------------------------
__global__ __launch_bounds__(256) void wt_kernel(
    const float* __restrict__ wq, const float* __restrict__ wk,
    const float* __restrict__ wv, const float* __restrict__ wg,
    const float* __restrict__ wo, __bf16* __restrict__ wTg,
    _Float16* __restrict__ woh)
{
    const int mat = blockIdx.x >> 3, seg = blockIdx.x & 7;
    if (mat == 4) {
        #pragma unroll
        for (int rep = 0; rep < 8; ++rep) {
            const int idx = seg * 2048 + rep * 256 + threadIdx.x;
            woh[idx] = (_Float16)wo[idx];
        }
        return;
    }
    const float* __restrict__ ws_ = (mat == 0) ? wq : (mat == 1) ? wk
                                  : (mat == 2) ? wv : wg;
    #pragma unroll
    for (int rep = 0; rep < 8; ++rep) {
        const int idx = seg * 2048 + rep * 256 + threadIdx.x;
        const int n = idx >> 7, c = idx & 127;
        wTg[mat * 16384 + n * 128 + c] = (__bf16)ws_[c * 128 + n];
    }
}

// ---------------------------------------------------------------------------
// K1: transpose + LayerNorm -> xn bf16, plus tri-bias (PRE-PERMUTED tbp).
// 32 lanes per row: float4 loads, shfl depth 5, 2 rows/wave, grid 8192.
// Row r = a*256+b holds LN(x[b,a,:]); tbp layout (HW-validated R4):
// value (h,j=a,k=b) -> tbp[((h*16+jb)*64+lnA)*64+slot],
// jb=a>>4, lnA=(b&15)|(((a&15)>>2)<<4), slot=((b>>4)<<2)|(a&3).
// ---------------------------------------------------------------------------
__global__ __launch_bounds__(256) void ln_kernel(
    const float* __restrict__ x, const float* __restrict__ lnw,
    const float* __restrict__ lnb, const float* __restrict__ wbias,
    __bf16* __restrict__ xn, float* __restrict__ tbp)
{
    const int t = threadIdx.x;
    const int wv = t >> 6, half = (t >> 5) & 1, lane = t & 31;
    const int r = blockIdx.x * 8 + wv * 2 + half;
    const int a = r >> 8, b = r & 255;   // tb value for (h, j=a, k=b)

    const float4 v = *(const float4*)&x[((size_t)b * N + a) * C + lane * 4];
    float s  = v.x + v.y + v.z + v.w;
    float ss = v.x*v.x + v.y*v.y + v.z*v.z + v.w*v.w;
    #pragma unroll
    for (int o = 16; o; o >>= 1) {
        s  += __shfl_xor(s,  o);
        ss += __shfl_xor(ss, o);
    }
    const float mu  = s * (1.0f / 128.0f);
    const float var = ss * (1.0f / 128.0f) - mu * mu;
    const float rs  = rsqrtf(var + LN_EPS);

    const float4 lw = *(const float4*)&lnw[lane * 4];
    const float4 lb = *(const float4*)&lnb[lane * 4];
    const float y0 = (v.x - mu) * rs * lw.x + lb.x;
    const float y1 = (v.y - mu) * rs * lw.y + lb.y;
    const float y2 = (v.z - mu) * rs * lw.z + lb.z;
    const float y3 = (v.w - mu) * rs * lw.w + lb.w;

    bf16x4 xo;
    xo[0] = (__bf16)y0; xo[1] = (__bf16)y1;
    xo[2] = (__bf16)y2; xo[3] = (__bf16)y3;
    *(bf16x4*)&xn[(size_t)r * C + lane * 4] = xo;

    // permuted tb address components for (j=a, k=b)
    const int jb   = a >> 4;                             // 16-row j-tile
    const int lnA  = (b & 15) | (((a & 15) >> 2) << 4);  // attn lane
    const int slot = ((b >> 4) << 2) | (a & 3);          // kt*4 + r
    #pragma unroll
    for (int hh = 0; hh < H; ++hh) {
        const float4 wb4 = *(const float4*)&wbias[hh * C + lane * 4];
        float tv = y0 * wb4.x + y1 * wb4.y + y2 * wb4.z + y3 * wb4.w;
        #pragma unroll
        for (int o = 16; o; o >>= 1) tv += __shfl_xor(tv, o);
        if (lane == 0)
            tbp[(size_t)(((hh * 16 + jb) * 64 + lnA) * 64 + slot)] = tv;
    }
}

// ---------------------------------------------------------------------------
// K2: projection GEMM — ALL 4 MATS PER BLOCK (was blockIdx.y = mat, which
// streamed the full 16.8 MB xn from L3 four times = 67 MB of reads).
// The mat loop is now inside the kernel: the A-tile addresses repeat
// exactly across mats, so passes 2-4 hit L1/L2; xn L3-traffic drops 4x.
// Register pressure unchanged (one mat's Cf at a time); Cs is wave-private
// (no barriers); grid 2048 -> 512 blocks; inner code identical to proven.
// ---------------------------------------------------------------------------
__global__ __launch_bounds__(256, 3) void proj_kernel(
    const __bf16* __restrict__ xn, const __bf16* __restrict__ wTg,
    __bf16* __restrict__ qbuf, __bf16* __restrict__ kbuf,
    __bf16* __restrict__ vbuf, __bf16* __restrict__ gbuf)
{
    __shared__ __bf16 Cs[4][64 * 72];

    const int t = threadIdx.x, w = t >> 6, lane = t & 63;
    const int ln16 = lane & 15, quad = lane >> 4;
    const int wr = w >> 1, wc = w & 1;
    const int m_base = blockIdx.x * 128 + wr * 64;
    const int n_base = wc * 64;
    const floatx4 z4 = {0.f, 0.f, 0.f, 0.f};

    const int m = m_base + lane;
    const int i = m >> 8, jk = m & 255;
    __bf16* __restrict__ Cw = &Cs[w][0];

    #pragma unroll 1
    for (int mat = 0; mat < 4; ++mat) {
        const __bf16* __restrict__ wT = wTg + mat * 16384;

        floatx4 Cf[4][4];
        #pragma unroll
        for (int mt = 0; mt < 4; ++mt)
            #pragma unroll
            for (int nt = 0; nt < 4; ++nt) Cf[mt][nt] = z4;

        #pragma unroll
        for (int ks = 0; ks < 4; ++ks) {
            bf16x8 Af[4], Bf[4];
            #pragma unroll
            for (int mt = 0; mt < 4; ++mt)
                Af[mt] = *(const bf16x8*)&xn[(size_t)(m_base + mt*16 + ln16) * 128 + ks*32 + quad*8];
            #pragma unroll
            for (int nt = 0; nt < 4; ++nt)
                Bf[nt] = *(const bf16x8*)&wT[(n_base + nt*16 + ln16) * 128 + ks*32 + quad*8];
            #pragma unroll
            for (int mt = 0; mt < 4; ++mt)
                #pragma unroll
                for (int nt = 0; nt < 4; ++nt)
                    Cf[mt][nt] = mfma16(Af[mt], Bf[nt], Cf[mt][nt]);
        }

        const float scl = (mat == 0) ? SCALE : 1.0f;
        #pragma unroll
        for (int mt = 0; mt < 4; ++mt)
            #pragma unroll
            for (int nt = 0; nt < 4; ++nt)
                #pragma unroll
                for (int r = 0; r < 4; ++r)
                    Cw[(mt*16 + quad*4 + r) * 72 + nt*16 + ln16] =
                        (__bf16)(Cf[mt][nt][r] * scl);

        __bf16* __restrict__ dst = (mat == 0) ? qbuf : (mat == 1) ? kbuf
                                 : (mat == 2) ? vbuf : gbuf;
        #pragma unroll
        for (int hf = 0; hf < 2; ++hf) {
            const int hh = wc * 2 + hf;
            __bf16* __restrict__ drow = dst + (((size_t)i*4 + hh)*256 + jk)*32;
            #pragma unroll
            for (int u = 0; u < 4; ++u)
                *(bf16x8*)&drow[u*8] = *(const bf16x8*)&Cw[lane*72 + hf*32 + u*8];
        }
    }
}

// ---------------------------------------------------------------------------
// K3: MFMA attention — EXACT R10 kernel (best attn: 65.4 us, zero spill).
// attn is at a structural floor for this algorithm family: residency
// 2/3/4 blocks identical (R8/9/10), 8-wave chain-split worse (R12),
// register-paid DS cuts spill past the ~128-VGPR ceiling (R11), swapped-QK
// restructure worse (R5-R7). Parked.
// Ks XOR-swizzled; Pw 32-key chunks; bias folded into MFMA C (R6);
// K LDS-staged (R3); launch bounds (256,2) (R5). Rule #20 throughout.
// ---------------------------------------------------------------------------
__global__ __launch_bounds__(256, 2) void attn_kernel(
    const float* __restrict__ tbp, const float* __restrict__ mask,
    const float* __restrict__ bg,
    const __bf16* __restrict__ qbuf, const __bf16* __restrict__ kbuf,
    const __bf16* __restrict__ vbuf, const __bf16* __restrict__ gbuf,
    _Float16* __restrict__ ogh)
{
    const int bid = blockIdx.x;
    const int i = bid & 255, h = bid >> 8;
    const int t = threadIdx.x, w = t >> 6, lane = t & 63;
    const int ln16 = lane & 15, quad = lane >> 4;

    __shared__ __align__(16) __bf16 Ks[256 * 32];      // 16384 B (swizzled)
    __shared__ __align__(16) __bf16 VT[32 * 264];      // 16896 B
    __shared__ __align__(16) __bf16 Pw[4][16 * 40];    //  5120 B
    __shared__ float mb[256];                          //  1024 B

    const size_t hb = (size_t)i * 4 + h;
    const __bf16* __restrict__ qb = qbuf + hb * 8192;
    const __bf16* __restrict__ kb = kbuf + hb * 8192;
    const __bf16* __restrict__ vb = vbuf + hb * 8192;
    const __bf16* __restrict__ gb = gbuf + hb * 8192;

    // K staging: swizzled 16B-block placement
    {
        const int xt = (t & 3) ^ ((t >> 2) & 3);
        #pragma unroll
        for (int u = 0; u < 4; ++u)
            *(bf16x8*)&Ks[t * 32 + ((u ^ xt) * 8)] = *(const bf16x8*)&kb[t * 32 + u * 8];
    }
    #pragma unroll
    for (int u = 0; u < 4; ++u) {
        const bf16x8 vv = *(const bf16x8*)&vb[t * 32 + u * 8];
        #pragma unroll
        for (int e = 0; e < 8; ++e) VT[(u*8 + e) * 264 + t] = vv[e];
    }
    mb[t] = INFB * (mask[(size_t)t * N + i] - 1.0f);
    __syncthreads();

    const float bg0 = bg[h*32 + ln16], bg1 = bg[h*32 + 16 + ln16];

    float mbv[16];
    #pragma unroll
    for (int kt = 0; kt < 16; ++kt) mbv[kt] = mb[kt*16 + ln16];

    // per-lane constant swizzled K-block offset
    const int kq = ((quad ^ ((ln16 & 3) ^ ((ln16 >> 2) & 3))) * 8);

    __bf16* __restrict__ Pww = &Pw[w][0];
    const floatx4 z4 = {0.f, 0.f, 0.f, 0.f};
    _Float16* __restrict__ ogb = ogh + ((size_t)h * 256 + i) * 8192;

    #pragma unroll 1
    for (int jt = 0; jt < 4; ++jt) {
        const int jrow0 = w*64 + jt*16;
        // per-lane contiguous 256B slab of pre-permuted tri-bias
        const float* __restrict__ tbl =
            tbp + ((size_t)((h*16 + (w*4 + jt))*64 + lane) << 6);
        const bf16x8 Qf = *(const bf16x8*)&qb[(jrow0 + ln16)*32 + quad*8];

        // ---- scores with bias folded into the MFMA C-operand ----
        floatx4 S[16];
        #pragma unroll
        for (int kt = 0; kt < 16; ++kt) {
            const float4 tb4 = *(const float4*)&tbl[kt*4];
            const float mbk = mbv[kt];
            floatx4 c;
            c[0] = mbk + tb4.x;
            c[1] = mbk + tb4.y;
            c[2] = mbk + tb4.z;
            c[3] = mbk + tb4.w;
            const bf16x8 Kf = *(const bf16x8*)&Ks[(kt*16 + ln16)*32 + kq];
            S[kt] = mfma16(Qf, Kf, c);
        }

        // ---- full-row softmax (16-lane shfl reduce) ----
        float mrow[4], l[4];
        #pragma unroll
        for (int r = 0; r < 4; ++r) {
            float mx = S[0][r];
            #pragma unroll
            for (int kt = 1; kt < 16; ++kt) mx = fmaxf(mx, S[kt][r]);
            #pragma unroll
            for (int off = 1; off < 16; off <<= 1) mx = fmaxf(mx, __shfl_xor(mx, off));
            mrow[r] = mx; l[r] = 0.f;
        }
        #pragma unroll
        for (int kt = 0; kt < 16; ++kt)
            #pragma unroll
            for (int r = 0; r < 4; ++r) {
                const float p = __expf(S[kt][r] - mrow[r]);
                S[kt][r] = p; l[r] += p;
            }
        #pragma unroll
        for (int r = 0; r < 4; ++r)
            #pragma unroll
            for (int off = 1; off < 16; off <<= 1) l[r] += __shfl_xor(l[r], off);

        // ---- PV in 8 key-chunks of 32: P-chunk -> LDS, 1 MFMA pair each ----
        floatx4 O0 = z4, O1 = z4;
        #pragma unroll
        for (int ch = 0; ch < 8; ++ch) {
            #pragma unroll
            for (int kk = 0; kk < 2; ++kk) {
                const int kt = ch*2 + kk;
                #pragma unroll
                for (int r = 0; r < 4; ++r)
                    Pww[(quad*4 + r)*40 + kk*16 + ln16] = (__bf16)S[kt][r];
            }
            const bf16x8 Af = *(const bf16x8*)&Pww[ln16*40 + quad*8];
            const bf16x8 V0 = *(const bf16x8*)&VT[ln16*264 + ch*32 + quad*8];
            const bf16x8 V1 = *(const bf16x8*)&VT[(16 + ln16)*264 + ch*32 + quad*8];
            O0 = mfma16(Af, V0, O0);
            O1 = mfma16(Af, V1, O1);
        }

        // ---- normalize+gate -> fp16 repack in wave-private LDS ----
        _Float16* Po = (_Float16*)Pww;
        #pragma unroll
        for (int r = 0; r < 4; ++r) {
            const float inv = 1.0f / l[r];
            const int jrow = jrow0 + quad*4 + r;
            const float g0 = (float)gb[jrow*32 + ln16];
            const float g1 = (float)gb[jrow*32 + 16 + ln16];
            const float gate0 = 1.0f / (1.0f + __expf(-(g0 + bg0)));
            const float gate1 = 1.0f / (1.0f + __expf(-(g1 + bg1)));
            Po[(quad*4 + r)*40 + ln16]      = (_Float16)(O0[r] * inv * gate0);
            Po[(quad*4 + r)*40 + 16 + ln16] = (_Float16)(O1[r] * inv * gate1);
        }
        // contiguous 1KB-per-wave store (in-order DS pipe, wave-private)
        {
            const int rr = lane >> 2, cc = lane & 3;
            const halfx8 ov = *(const halfx8*)&Po[rr*40 + cc*8];
            *(halfx8*)&ogb[(size_t)(jrow0 + rr)*32 + cc*8] = ov;
        }
    }
}

// ---------------------------------------------------------------------------
// K4: output projection as f16 MFMA GEMM: out[(j*256+i)*128 + c] =
// sum_k og[(i*256+j), k] * woh[c, k] + bo[c], k = h*32+d over 4 head-slices.
// No LDS; A from og fp16 (coalesced), B from woh (L2-resident).
// ---------------------------------------------------------------------------
__global__ __launch_bounds__(256, 4) void outproj_kernel(
    const _Float16* __restrict__ og, const _Float16* __restrict__ woh,
    const float* __restrict__ bo, float* __restrict__ out)
{
    const int t = threadIdx.x, w = t >> 6, lane = t & 63;
    const int ln16 = lane & 15, quad = lane >> 4;
    const int wr = w >> 1, wc = w & 1;
    const int m_base = blockIdx.x * 128 + wr * 64;
    const int n_base = wc * 64;

    floatx4 Cf[4][4];
    const floatx4 z4 = {0.f, 0.f, 0.f, 0.f};
    #pragma unroll
    for (int mt = 0; mt < 4; ++mt)
        #pragma unroll
        for (int nt = 0; nt < 4; ++nt) Cf[mt][nt] = z4;

    #pragma unroll
    for (int ks = 0; ks < 4; ++ks) {   // ks = head
        halfx8 Af[4], Bf[4];
        #pragma unroll
        for (int mt = 0; mt < 4; ++mt)
            Af[mt] = *(const halfx8*)&og[(size_t)ks*2097152 + (size_t)(m_base + mt*16 + ln16)*32 + quad*8];
        #pragma unroll
        for (int nt = 0; nt < 4; ++nt)
            Bf[nt] = *(const halfx8*)&woh[(n_base + nt*16 + ln16)*128 + ks*32 + quad*8];
        #pragma unroll
        for (int mt = 0; mt < 4; ++mt)
            #pragma unroll
            for (int nt = 0; nt < 4; ++nt)
                Cf[mt][nt] = mfma16h(Af[mt], Bf[nt], Cf[mt][nt]);
    }

    float bov[4];
    #pragma unroll
    for (int nt = 0; nt < 4; ++nt) bov[nt] = bo[n_base + nt*16 + ln16];

    #pragma unroll
    for (int mt = 0; mt < 4; ++mt)
        #pragma unroll
        for (int r = 0; r < 4; ++r) {
            const int m = m_base + mt*16 + quad*4 + r;
            const size_t orow = (size_t)(m & 255) * 256 + (m >> 8);  // (j,i)
            #pragma unroll
            for (int nt = 0; nt < 4; ++nt)
                out[orow*128 + n_base + nt*16 + ln16] = Cf[mt][nt][r] + bov[nt];
        }
}

// ---------------------------------------------------------------------------
extern "C" void kernel_launch(void* const* d_in, const int* in_sizes, int n_in,
                              void* d_out, int out_size, void* d_ws, size_t ws_size,
                              hipStream_t stream) {
    const float* x     = (const float*)d_in[0];
    const float* mask  = (const float*)d_in[1];
    const float* lnw   = (const float*)d_in[2];
    const float* lnb   = (const float*)d_in[3];
    const float* wbias = (const float*)d_in[4];
    const float* wq    = (const float*)d_in[5];
    const float* wk    = (const float*)d_in[6];
    const float* wv    = (const float*)d_in[7];
    const float* wg    = (const float*)d_in[8];
    const float* bg    = (const float*)d_in[9];
    const float* wo    = (const float*)d_in[10];
    const float* bo    = (const float*)d_in[11];
    float* out = (float*)d_out;

    char* wsb = (char*)d_ws;
    __bf16*    xn   = (__bf16*)   (wsb);              // 16.78 MB
    float*     tbp  = (float*)    (wsb + 16777216);   //  1.05 MB (permuted)
    __bf16*    wTg  = (__bf16*)   (wsb + 17825792);   //  0.13 MB
    _Float16*  woh  = (_Float16*) (wsb + 17956864);   //  0.03 MB
    __bf16*    qbuf = (__bf16*)   (wsb + 17989632);   // 16.78 MB
    __bf16*    kbuf = (__bf16*)   (wsb + 34766848);   // 16.78 MB
    __bf16*    vbuf = (__bf16*)   (wsb + 51544064);   // 16.78 MB
    __bf16*    gbuf = (__bf16*)   (wsb + 68321280);   // 16.78 MB
    _Float16*  ogh  = (_Float16*) (wsb + 85098496);   // 16.78 MB (total ~102 MB)

    wt_kernel<<<40, 256, 0, stream>>>(wq, wk, wv, wg, wo, wTg, woh);
    ln_kernel<<<8192, 256, 0, stream>>>(x, lnw, lnb, wbias, xn, tbp);
    proj_kernel<<<512, 256, 0, stream>>>(xn, wTg, qbuf, kbuf, vbuf, gbuf);
    attn_kernel<<<1024, 256, 0, stream>>>(tbp, mask, bg, qbuf, kbuf, vbuf, gbuf, ogh);
    outproj_kernel<<<512, 256, 0, stream>>>(ogh, woh, bo, out);
}

// Round 14
// 220.648 us; speedup vs baseline: 1.1228x; 1.0841x over previous
//
#include <hip/hip_runtime.h>

// Problem constants: B=1, N=256, C=128, H=4, D=32
#define N 256
#define C 128
#define H 4
#define D 32
#define LN_EPS 1e-5f
#define INFB 1e9f
#define SCALE 0.17677669529663687f  // 1/sqrt(32)

typedef __bf16 bf16x8 __attribute__((ext_vector_type(8)));
typedef __bf16 bf16x4 __attribute__((ext_vector_type(4)));
typedef __bf16 bf16x2 __attribute__((ext_vector_type(2)));
typedef _Float16 halfx8 __attribute__((ext_vector_type(8)));
typedef float floatx4 __attribute__((ext_vector_type(4)));

__device__ __forceinline__ floatx4 mfma16(bf16x8 a, bf16x8 b, floatx4 c) {
    return __builtin_amdgcn_mfma_f32_16x16x32_bf16(a, b, c, 0, 0, 0);
}
__device__ __forceinline__ floatx4 mfma16h(halfx8 a, halfx8 b, floatx4 c) {
    return __builtin_amdgcn_mfma_f32_16x16x32_f16(a, b, c, 0, 0, 0);
}

// ---------------------------------------------------------------------------
// K0: weight prep. mats 0..3: wTg[mat][n][c] = (bf16) w[c][n] (transposed).
// mat 4: woh[c][k] = (fp16) wo[c][k] (plain convert, layout kept k-major).
// ---------------------------------------------------------------------------
__global__ __launch_bounds__(256) void wt_kernel(
    const float* __restrict__ wq, const float* __restrict__ wk,
    const float* __restrict__ wv, const float* __restrict__ wg,
    const float* __restrict__ wo, __bf16* __restrict__ wTg,
    _Float16* __restrict__ woh)
{
    const int mat = blockIdx.x >> 3, seg = blockIdx.x & 7;
    if (mat == 4) {
        #pragma unroll
        for (int rep = 0; rep < 8; ++rep) {
            const int idx = seg * 2048 + rep * 256 + threadIdx.x;
            woh[idx] = (_Float16)wo[idx];
        }
        return;
    }
    const float* __restrict__ ws_ = (mat == 0) ? wq : (mat == 1) ? wk
                                  : (mat == 2) ? wv : wg;
    #pragma unroll
    for (int rep = 0; rep < 8; ++rep) {
        const int idx = seg * 2048 + rep * 256 + threadIdx.x;
        const int n = idx >> 7, c = idx & 127;
        wTg[mat * 16384 + n * 128 + c] = (__bf16)ws_[c * 128 + n];
    }
}

// ---------------------------------------------------------------------------
// K1+K2 FUSED: LayerNorm directly into an LDS A-tile, then the 4-mat
// projection GEMM from LDS. Key insight: proj's A-rows [blk*128,+128)
// depend ONLY on LN of those same rows (contraction is over C within a
// row), so the 16.8 MB xn buffer round-trip through L3 is unnecessary.
// R13 lesson: caching xn in L1 across a mat-loop fails (32KB tile thrashes
// 32KB L1); LDS is the right home for the reused A-tile.
// Phase 1: 16 passes x (4 waves x 2 rows) = 128 rows, 32 lanes/row,
//   float4 loads, shfl depth 5; bf16 result -> Als (stride 136: fragment
//   reads land 2-way bank aliases = free); tri-bias to global tbp
//   (PRE-PERMUTED layout, HW-validated R4): value (h,j=a,k=b) ->
//   tbp[((h*16+jb)*64+lnA)*64+slot], jb=a>>4, lnA=(b&15)|(((a&15)>>2)<<4),
//   slot=((b>>4)<<2)|(a&3).
// Phase 2: proven 2x2 64x64 wave tiling, mats looped, A from LDS, B from
//   L2-resident wTg, C via wave-private Cs repack (4KB-contiguous stores).
// LDS 71.7 KB -> 2 blocks/CU.
// ---------------------------------------------------------------------------
__global__ __launch_bounds__(256, 2) void lnproj_kernel(
    const float* __restrict__ x, const float* __restrict__ lnw,
    const float* __restrict__ lnb, const float* __restrict__ wbias,
    const __bf16* __restrict__ wTg, float* __restrict__ tbp,
    __bf16* __restrict__ qbuf, __bf16* __restrict__ kbuf,
    __bf16* __restrict__ vbuf, __bf16* __restrict__ gbuf)
{
    __shared__ __align__(16) __bf16 Als[128 * 136];   // 34816 B
    __shared__ __align__(16) __bf16 Cs[4][64 * 72];   // 36864 B

    const int t = threadIdx.x;
    const int blk = blockIdx.x;

    // ---- Phase 1: LN of this block's 128 rows -> Als (+ tbp) ----
    {
        const int wv = t >> 6, half = (t >> 5) & 1, lane = t & 31;
        #pragma unroll 1
        for (int p = 0; p < 16; ++p) {
            const int rl = p * 8 + wv * 2 + half;
            const int r = blk * 128 + rl;
            const int a = r >> 8, b = r & 255;   // value (h, j=a, k=b)

            const float4 v = *(const float4*)&x[((size_t)b * N + a) * C + lane * 4];
            float s  = v.x + v.y + v.z + v.w;
            float ss = v.x*v.x + v.y*v.y + v.z*v.z + v.w*v.w;
            #pragma unroll
            for (int o = 16; o; o >>= 1) {
                s  += __shfl_xor(s,  o);
                ss += __shfl_xor(ss, o);
            }
            const float mu  = s * (1.0f / 128.0f);
            const float var = ss * (1.0f / 128.0f) - mu * mu;
            const float rs  = rsqrtf(var + LN_EPS);

            const float4 lw = *(const float4*)&lnw[lane * 4];
            const float4 lb = *(const float4*)&lnb[lane * 4];
            const float y0 = (v.x - mu) * rs * lw.x + lb.x;
            const float y1 = (v.y - mu) * rs * lw.y + lb.y;
            const float y2 = (v.z - mu) * rs * lw.z + lb.z;
            const float y3 = (v.w - mu) * rs * lw.w + lb.w;

            bf16x4 xo;
            xo[0] = (__bf16)y0; xo[1] = (__bf16)y1;
            xo[2] = (__bf16)y2; xo[3] = (__bf16)y3;
            *(bf16x4*)&Als[rl * 136 + lane * 4] = xo;

            // permuted tb address components for (j=a, k=b)
            const int jb   = a >> 4;
            const int lnA  = (b & 15) | (((a & 15) >> 2) << 4);
            const int slot = ((b >> 4) << 2) | (a & 3);
            #pragma unroll
            for (int hh = 0; hh < H; ++hh) {
                const float4 wb4 = *(const float4*)&wbias[hh * C + lane * 4];
                float tv = y0 * wb4.x + y1 * wb4.y + y2 * wb4.z + y3 * wb4.w;
                #pragma unroll
                for (int o = 16; o; o >>= 1) tv += __shfl_xor(tv, o);
                if (lane == 0)
                    tbp[(size_t)(((hh * 16 + jb) * 64 + lnA) * 64 + slot)] = tv;
            }
        }
    }
    __syncthreads();

    // ---- Phase 2: 4-mat projection GEMM, A from LDS ----
    const int w = t >> 6, lane = t & 63;
    const int ln16 = lane & 15, quad = lane >> 4;
    const int wr = w >> 1, wc = w & 1;
    const int m_base_l = wr * 64;                 // local row base
    const int n_base = wc * 64;
    const floatx4 z4 = {0.f, 0.f, 0.f, 0.f};

    const int m = blk * 128 + m_base_l + lane;
    const int i = m >> 8, jk = m & 255;
    __bf16* __restrict__ Cw = &Cs[w][0];

    #pragma unroll 1
    for (int mat = 0; mat < 4; ++mat) {
        const __bf16* __restrict__ wT = wTg + mat * 16384;

        floatx4 Cf[4][4];
        #pragma unroll
        for (int mt = 0; mt < 4; ++mt)
            #pragma unroll
            for (int nt = 0; nt < 4; ++nt) Cf[mt][nt] = z4;

        #pragma unroll
        for (int ks = 0; ks < 4; ++ks) {
            bf16x8 Af[4], Bf[4];
            #pragma unroll
            for (int mt = 0; mt < 4; ++mt)
                Af[mt] = *(const bf16x8*)&Als[(m_base_l + mt*16 + ln16) * 136 + ks*32 + quad*8];
            #pragma unroll
            for (int nt = 0; nt < 4; ++nt)
                Bf[nt] = *(const bf16x8*)&wT[(n_base + nt*16 + ln16) * 128 + ks*32 + quad*8];
            #pragma unroll
            for (int mt = 0; mt < 4; ++mt)
                #pragma unroll
                for (int nt = 0; nt < 4; ++nt)
                    Cf[mt][nt] = mfma16(Af[mt], Bf[nt], Cf[mt][nt]);
        }

        const float scl = (mat == 0) ? SCALE : 1.0f;
        #pragma unroll
        for (int mt = 0; mt < 4; ++mt)
            #pragma unroll
            for (int nt = 0; nt < 4; ++nt)
                #pragma unroll
                for (int r = 0; r < 4; ++r)
                    Cw[(mt*16 + quad*4 + r) * 72 + nt*16 + ln16] =
                        (__bf16)(Cf[mt][nt][r] * scl);

        __bf16* __restrict__ dst = (mat == 0) ? qbuf : (mat == 1) ? kbuf
                                 : (mat == 2) ? vbuf : gbuf;
        #pragma unroll
        for (int hf = 0; hf < 2; ++hf) {
            const int hh = wc * 2 + hf;
            __bf16* __restrict__ drow = dst + (((size_t)i*4 + hh)*256 + jk)*32;
            #pragma unroll
            for (int u = 0; u < 4; ++u)
                *(bf16x8*)&drow[u*8] = *(const bf16x8*)&Cw[lane*72 + hf*32 + u*8];
        }
    }
}

// ---------------------------------------------------------------------------
// K3: MFMA attention — EXACT R10 kernel (best attn: 65.4 us, zero spill).
// attn is at a structural floor for this algorithm family: residency
// 2/3/4 blocks identical (R8/9/10), 8-wave chain-split worse (R12),
// register-paid DS cuts spill past the ~128-VGPR ceiling (R11), swapped-QK
// restructure worse (R5-R7). Parked.
// Ks XOR-swizzled; Pw 32-key chunks; bias folded into MFMA C (R6);
// K LDS-staged (R3); launch bounds (256,2) (R5). Rule #20 throughout.
// ---------------------------------------------------------------------------
__global__ __launch_bounds__(256, 2) void attn_kernel(
    const float* __restrict__ tbp, const float* __restrict__ mask,
    const float* __restrict__ bg,
    const __bf16* __restrict__ qbuf, const __bf16* __restrict__ kbuf,
    const __bf16* __restrict__ vbuf, const __bf16* __restrict__ gbuf,
    _Float16* __restrict__ ogh)
{
    const int bid = blockIdx.x;
    const int i = bid & 255, h = bid >> 8;
    const int t = threadIdx.x, w = t >> 6, lane = t & 63;
    const int ln16 = lane & 15, quad = lane >> 4;

    __shared__ __align__(16) __bf16 Ks[256 * 32];      // 16384 B (swizzled)
    __shared__ __align__(16) __bf16 VT[32 * 264];      // 16896 B
    __shared__ __align__(16) __bf16 Pw[4][16 * 40];    //  5120 B
    __shared__ float mb[256];                          //  1024 B

    const size_t hb = (size_t)i * 4 + h;
    const __bf16* __restrict__ qb = qbuf + hb * 8192;
    const __bf16* __restrict__ kb = kbuf + hb * 8192;
    const __bf16* __restrict__ vb = vbuf + hb * 8192;
    const __bf16* __restrict__ gb = gbuf + hb * 8192;

    // K staging: swizzled 16B-block placement
    {
        const int xt = (t & 3) ^ ((t >> 2) & 3);
        #pragma unroll
        for (int u = 0; u < 4; ++u)
            *(bf16x8*)&Ks[t * 32 + ((u ^ xt) * 8)] = *(const bf16x8*)&kb[t * 32 + u * 8];
    }
    #pragma unroll
    for (int u = 0; u < 4; ++u) {
        const bf16x8 vv = *(const bf16x8*)&vb[t * 32 + u * 8];
        #pragma unroll
        for (int e = 0; e < 8; ++e) VT[(u*8 + e) * 264 + t] = vv[e];
    }
    mb[t] = INFB * (mask[(size_t)t * N + i] - 1.0f);
    __syncthreads();

    const float bg0 = bg[h*32 + ln16], bg1 = bg[h*32 + 16 + ln16];

    float mbv[16];
    #pragma unroll
    for (int kt = 0; kt < 16; ++kt) mbv[kt] = mb[kt*16 + ln16];

    // per-lane constant swizzled K-block offset
    const int kq = ((quad ^ ((ln16 & 3) ^ ((ln16 >> 2) & 3))) * 8);

    __bf16* __restrict__ Pww = &Pw[w][0];
    const floatx4 z4 = {0.f, 0.f, 0.f, 0.f};
    _Float16* __restrict__ ogb = ogh + ((size_t)h * 256 + i) * 8192;

    #pragma unroll 1
    for (int jt = 0; jt < 4; ++jt) {
        const int jrow0 = w*64 + jt*16;
        // per-lane contiguous 256B slab of pre-permuted tri-bias
        const float* __restrict__ tbl =
            tbp + ((size_t)((h*16 + (w*4 + jt))*64 + lane) << 6);
        const bf16x8 Qf = *(const bf16x8*)&qb[(jrow0 + ln16)*32 + quad*8];

        // ---- scores with bias folded into the MFMA C-operand ----
        floatx4 S[16];
        #pragma unroll
        for (int kt = 0; kt < 16; ++kt) {
            const float4 tb4 = *(const float4*)&tbl[kt*4];
            const float mbk = mbv[kt];
            floatx4 c;
            c[0] = mbk + tb4.x;
            c[1] = mbk + tb4.y;
            c[2] = mbk + tb4.z;
            c[3] = mbk + tb4.w;
            const bf16x8 Kf = *(const bf16x8*)&Ks[(kt*16 + ln16)*32 + kq];
            S[kt] = mfma16(Qf, Kf, c);
        }

        // ---- full-row softmax (16-lane shfl reduce) ----
        float mrow[4], l[4];
        #pragma unroll
        for (int r = 0; r < 4; ++r) {
            float mx = S[0][r];
            #pragma unroll
            for (int kt = 1; kt < 16; ++kt) mx = fmaxf(mx, S[kt][r]);
            #pragma unroll
            for (int off = 1; off < 16; off <<= 1) mx = fmaxf(mx, __shfl_xor(mx, off));
            mrow[r] = mx; l[r] = 0.f;
        }
        #pragma unroll
        for (int kt = 0; kt < 16; ++kt)
            #pragma unroll
            for (int r = 0; r < 4; ++r) {
                const float p = __expf(S[kt][r] - mrow[r]);
                S[kt][r] = p; l[r] += p;
            }
        #pragma unroll
        for (int r = 0; r < 4; ++r)
            #pragma unroll
            for (int off = 1; off < 16; off <<= 1) l[r] += __shfl_xor(l[r], off);

        // ---- PV in 8 key-chunks of 32: P-chunk -> LDS, 1 MFMA pair each ----
        floatx4 O0 = z4, O1 = z4;
        #pragma unroll
        for (int ch = 0; ch < 8; ++ch) {
            #pragma unroll
            for (int kk = 0; kk < 2; ++kk) {
                const int kt = ch*2 + kk;
                #pragma unroll
                for (int r = 0; r < 4; ++r)
                    Pww[(quad*4 + r)*40 + kk*16 + ln16] = (__bf16)S[kt][r];
            }
            const bf16x8 Af = *(const bf16x8*)&Pww[ln16*40 + quad*8];
            const bf16x8 V0 = *(const bf16x8*)&VT[ln16*264 + ch*32 + quad*8];
            const bf16x8 V1 = *(const bf16x8*)&VT[(16 + ln16)*264 + ch*32 + quad*8];
            O0 = mfma16(Af, V0, O0);
            O1 = mfma16(Af, V1, O1);
        }

        // ---- normalize+gate -> fp16 repack in wave-private LDS ----
        _Float16* Po = (_Float16*)Pww;
        #pragma unroll
        for (int r = 0; r < 4; ++r) {
            const float inv = 1.0f / l[r];
            const int jrow = jrow0 + quad*4 + r;
            const float g0 = (float)gb[jrow*32 + ln16];
            const float g1 = (float)gb[jrow*32 + 16 + ln16];
            const float gate0 = 1.0f / (1.0f + __expf(-(g0 + bg0)));
            const float gate1 = 1.0f / (1.0f + __expf(-(g1 + bg1)));
            Po[(quad*4 + r)*40 + ln16]      = (_Float16)(O0[r] * inv * gate0);
            Po[(quad*4 + r)*40 + 16 + ln16] = (_Float16)(O1[r] * inv * gate1);
        }
        // contiguous 1KB-per-wave store (in-order DS pipe, wave-private)
        {
            const int rr = lane >> 2, cc = lane & 3;
            const halfx8 ov = *(const halfx8*)&Po[rr*40 + cc*8];
            *(halfx8*)&ogb[(size_t)(jrow0 + rr)*32 + cc*8] = ov;
        }
    }
}

// ---------------------------------------------------------------------------
// K4: output projection as f16 MFMA GEMM: out[(j*256+i)*128 + c] =
// sum_k og[(i*256+j), k] * woh[c, k] + bo[c], k = h*32+d over 4 head-slices.
// No LDS; A from og fp16 (coalesced), B from woh (L2-resident).
// ---------------------------------------------------------------------------
__global__ __launch_bounds__(256, 4) void outproj_kernel(
    const _Float16* __restrict__ og, const _Float16* __restrict__ woh,
    const float* __restrict__ bo, float* __restrict__ out)
{
    const int t = threadIdx.x, w = t >> 6, lane = t & 63;
    const int ln16 = lane & 15, quad = lane >> 4;
    const int wr = w >> 1, wc = w & 1;
    const int m_base = blockIdx.x * 128 + wr * 64;
    const int n_base = wc * 64;

    floatx4 Cf[4][4];
    const floatx4 z4 = {0.f, 0.f, 0.f, 0.f};
    #pragma unroll
    for (int mt = 0; mt < 4; ++mt)
        #pragma unroll
        for (int nt = 0; nt < 4; ++nt) Cf[mt][nt] = z4;

    #pragma unroll
    for (int ks = 0; ks < 4; ++ks) {   // ks = head
        halfx8 Af[4], Bf[4];
        #pragma unroll
        for (int mt = 0; mt < 4; ++mt)
            Af[mt] = *(const halfx8*)&og[(size_t)ks*2097152 + (size_t)(m_base + mt*16 + ln16)*32 + quad*8];
        #pragma unroll
        for (int nt = 0; nt < 4; ++nt)
            Bf[nt] = *(const halfx8*)&woh[(n_base + nt*16 + ln16)*128 + ks*32 + quad*8];
        #pragma unroll
        for (int mt = 0; mt < 4; ++mt)
            #pragma unroll
            for (int nt = 0; nt < 4; ++nt)
                Cf[mt][nt] = mfma16h(Af[mt], Bf[nt], Cf[mt][nt]);
    }

    float bov[4];
    #pragma unroll
    for (int nt = 0; nt < 4; ++nt) bov[nt] = bo[n_base + nt*16 + ln16];

    #pragma unroll
    for (int mt = 0; mt < 4; ++mt)
        #pragma unroll
        for (int r = 0; r < 4; ++r) {
            const int m = m_base + mt*16 + quad*4 + r;
            const size_t orow = (size_t)(m & 255) * 256 + (m >> 8);  // (j,i)
            #pragma unroll
            for (int nt = 0; nt < 4; ++nt)
                out[orow*128 + n_base + nt*16 + ln16] = Cf[mt][nt][r] + bov[nt];
        }
}

// ---------------------------------------------------------------------------
extern "C" void kernel_launch(void* const* d_in, const int* in_sizes, int n_in,
                              void* d_out, int out_size, void* d_ws, size_t ws_size,
                              hipStream_t stream) {
    const float* x     = (const float*)d_in[0];
    const float* mask  = (const float*)d_in[1];
    const float* lnw   = (const float*)d_in[2];
    const float* lnb   = (const float*)d_in[3];
    const float* wbias = (const float*)d_in[4];
    const float* wq    = (const float*)d_in[5];
    const float* wk    = (const float*)d_in[6];
    const float* wv    = (const float*)d_in[7];
    const float* wg    = (const float*)d_in[8];
    const float* bg    = (const float*)d_in[9];
    const float* wo    = (const float*)d_in[10];
    const float* bo    = (const float*)d_in[11];
    float* out = (float*)d_out;

    char* wsb = (char*)d_ws;
    float*     tbp  = (float*)    (wsb + 16777216);   //  1.05 MB (permuted)
    __bf16*    wTg  = (__bf16*)   (wsb + 17825792);   //  0.13 MB
    _Float16*  woh  = (_Float16*) (wsb + 17956864);   //  0.03 MB
    __bf16*    qbuf = (__bf16*)   (wsb + 17989632);   // 16.78 MB
    __bf16*    kbuf = (__bf16*)   (wsb + 34766848);   // 16.78 MB
    __bf16*    vbuf = (__bf16*)   (wsb + 51544064);   // 16.78 MB
    __bf16*    gbuf = (__bf16*)   (wsb + 68321280);   // 16.78 MB
    _Float16*  ogh  = (_Float16*) (wsb + 85098496);   // 16.78 MB

    wt_kernel<<<40, 256, 0, stream>>>(wq, wk, wv, wg, wo, wTg, woh);
    lnproj_kernel<<<512, 256, 0, stream>>>(x, lnw, lnb, wbias, wTg, tbp,
                                           qbuf, kbuf, vbuf, gbuf);
    attn_kernel<<<1024, 256, 0, stream>>>(tbp, mask, bg, qbuf, kbuf, vbuf, gbuf, ogh);
    outproj_kernel<<<512, 256, 0, stream>>>(ogh, woh, bo, out);
}

// Round 15
// 217.927 us; speedup vs baseline: 1.1368x; 1.0125x over previous
//
#include <hip/hip_runtime.h>

// Problem constants: B=1, N=256, C=128, H=4, D=32
#define N 256
#define C 128
#define H 4
#define D 32
#define LN_EPS 1e-5f
#define INFB 1e9f
#define SCALE 0.17677669529663687f  // 1/sqrt(32)

typedef __bf16 bf16x8 __attribute__((ext_vector_type(8)));
typedef __bf16 bf16x4 __attribute__((ext_vector_type(4)));
typedef __bf16 bf16x2 __attribute__((ext_vector_type(2)));
typedef _Float16 halfx8 __attribute__((ext_vector_type(8)));
typedef float floatx4 __attribute__((ext_vector_type(4)));

__device__ __forceinline__ floatx4 mfma16(bf16x8 a, bf16x8 b, floatx4 c) {
    return __builtin_amdgcn_mfma_f32_16x16x32_bf16(a, b, c, 0, 0, 0);
}
__device__ __forceinline__ floatx4 mfma16h(halfx8 a, halfx8 b, floatx4 c) {
    return __builtin_amdgcn_mfma_f32_16x16x32_f16(a, b, c, 0, 0, 0);
}

// ---------------------------------------------------------------------------
// K0: weight prep. mats 0..3: wTg[mat][n][c] = (bf16) w[c][n] (transposed).
// mat 4: woh[c][k] = (fp16) wo[c][k] (plain convert, layout kept k-major).
// ---------------------------------------------------------------------------
__global__ __launch_bounds__(256) void wt_kernel(
    const float* __restrict__ wq, const float* __restrict__ wk,
    const float* __restrict__ wv, const float* __restrict__ wg,
    const float* __restrict__ wo, __bf16* __restrict__ wTg,
    _Float16* __restrict__ woh)
{
    const int mat = blockIdx.x >> 3, seg = blockIdx.x & 7;
    if (mat == 4) {
        #pragma unroll
        for (int rep = 0; rep < 8; ++rep) {
            const int idx = seg * 2048 + rep * 256 + threadIdx.x;
            woh[idx] = (_Float16)wo[idx];
        }
        return;
    }
    const float* __restrict__ ws_ = (mat == 0) ? wq : (mat == 1) ? wk
                                  : (mat == 2) ? wv : wg;
    #pragma unroll
    for (int rep = 0; rep < 8; ++rep) {
        const int idx = seg * 2048 + rep * 256 + threadIdx.x;
        const int n = idx >> 7, c = idx & 127;
        wTg[mat * 16384 + n * 128 + c] = (__bf16)ws_[c * 128 + n];
    }
}

// ---------------------------------------------------------------------------
// K1+K2 FUSED: LayerNorm -> LDS A-tile -> 4-mat projection GEMM (R14 win).
// Phase 1 RESHAPED this round: was 16 serial passes x depth-5 shfl chains
// (32 lanes/row) — a serial-latency tail carried over from the standalone
// grid-8192 ln kernel, unexamined under the fused grid-512 geometry.
// Now 4 LANES PER ROW x 2 PASSES: each thread owns 32 channels (8 float4
// in regs), reductions are depth-2 shfl (xor 1,2), and tri-bias dots are
// accumulated in the same u-loop where y is produced (each wb4 load dies
// into its FMAs — R6 liveness discipline; peak ~80 VGPR).
// Serial chain per block drops ~4-5x. Als/tbp layouts byte-identical.
// tbp (PRE-PERMUTED, HW-validated R4): value (h,j=a,k=b) ->
// tbp[((h*16+jb)*64+lnA)*64+slot], jb=a>>4, lnA=(b&15)|(((a&15)>>2)<<4),
// slot=((b>>4)<<2)|(a&3).
// Phase 2 (unchanged): proven 2x2 64x64 wave tiling, mats looped, A from
// LDS (stride 136), B from L2-resident wTg, Cs repack epilogue.
// LDS 71.7 KB -> 2 blocks/CU.
// ---------------------------------------------------------------------------
__global__ __launch_bounds__(256, 2) void lnproj_kernel(
    const float* __restrict__ x, const float* __restrict__ lnw,
    const float* __restrict__ lnb, const float* __restrict__ wbias,
    const __bf16* __restrict__ wTg, float* __restrict__ tbp,
    __bf16* __restrict__ qbuf, __bf16* __restrict__ kbuf,
    __bf16* __restrict__ vbuf, __bf16* __restrict__ gbuf)
{
    __shared__ __align__(16) __bf16 Als[128 * 136];   // 34816 B
    __shared__ __align__(16) __bf16 Cs[4][64 * 72];   // 36864 B

    const int t = threadIdx.x;
    const int blk = blockIdx.x;

    // ---- Phase 1: LN of 128 rows -> Als (+ tbp), 4 lanes/row, 2 passes ----
    {
        const int q4 = t & 3;
        #pragma unroll 1
        for (int p = 0; p < 2; ++p) {
            const int rl = p * 64 + (t >> 2);
            const int r = blk * 128 + rl;
            const int a = r >> 8, b = r & 255;   // value (h, j=a, k=b)
            const float* __restrict__ xr = &x[((size_t)b * N + a) * C + q4 * 32];

            float4 v[8];
            #pragma unroll
            for (int u = 0; u < 8; ++u) v[u] = *(const float4*)&xr[u * 4];

            float s = 0.f, ss = 0.f;
            #pragma unroll
            for (int u = 0; u < 8; ++u) {
                s  += (v[u].x + v[u].y) + (v[u].z + v[u].w);
                ss += (v[u].x*v[u].x + v[u].y*v[u].y) + (v[u].z*v[u].z + v[u].w*v[u].w);
            }
            s  += __shfl_xor(s, 1);  s  += __shfl_xor(s, 2);
            ss += __shfl_xor(ss, 1); ss += __shfl_xor(ss, 2);
            const float mu  = s * (1.0f / 128.0f);
            const float var = ss * (1.0f / 128.0f) - mu * mu;
            const float rs  = rsqrtf(var + LN_EPS);

            float tv0 = 0.f, tv1 = 0.f, tv2 = 0.f, tv3 = 0.f;
            #pragma unroll
            for (int u = 0; u < 8; ++u) {
                const float4 lw = *(const float4*)&lnw[q4*32 + u*4];
                const float4 lb = *(const float4*)&lnb[q4*32 + u*4];
                float4 y;
                y.x = (v[u].x - mu) * rs * lw.x + lb.x;
                y.y = (v[u].y - mu) * rs * lw.y + lb.y;
                y.z = (v[u].z - mu) * rs * lw.z + lb.z;
                y.w = (v[u].w - mu) * rs * lw.w + lb.w;
                bf16x4 xo;
                xo[0] = (__bf16)y.x; xo[1] = (__bf16)y.y;
                xo[2] = (__bf16)y.z; xo[3] = (__bf16)y.w;
                *(bf16x4*)&Als[rl * 136 + q4 * 32 + u * 4] = xo;
                const float4 w0 = *(const float4*)&wbias[0*C + q4*32 + u*4];
                const float4 w1 = *(const float4*)&wbias[1*C + q4*32 + u*4];
                const float4 w2 = *(const float4*)&wbias[2*C + q4*32 + u*4];
                const float4 w3 = *(const float4*)&wbias[3*C + q4*32 + u*4];
                tv0 += (y.x*w0.x + y.y*w0.y) + (y.z*w0.z + y.w*w0.w);
                tv1 += (y.x*w1.x + y.y*w1.y) + (y.z*w1.z + y.w*w1.w);
                tv2 += (y.x*w2.x + y.y*w2.y) + (y.z*w2.z + y.w*w2.w);
                tv3 += (y.x*w3.x + y.y*w3.y) + (y.z*w3.z + y.w*w3.w);
            }
            tv0 += __shfl_xor(tv0, 1); tv0 += __shfl_xor(tv0, 2);
            tv1 += __shfl_xor(tv1, 1); tv1 += __shfl_xor(tv1, 2);
            tv2 += __shfl_xor(tv2, 1); tv2 += __shfl_xor(tv2, 2);
            tv3 += __shfl_xor(tv3, 1); tv3 += __shfl_xor(tv3, 2);

            if (q4 == 0) {
                const int jb   = a >> 4;
                const int lnA  = (b & 15) | (((a & 15) >> 2) << 4);
                const int slot = ((b >> 4) << 2) | (a & 3);
                tbp[(size_t)(((0*16 + jb) * 64 + lnA) * 64 + slot)] = tv0;
                tbp[(size_t)(((1*16 + jb) * 64 + lnA) * 64 + slot)] = tv1;
                tbp[(size_t)(((2*16 + jb) * 64 + lnA) * 64 + slot)] = tv2;
                tbp[(size_t)(((3*16 + jb) * 64 + lnA) * 64 + slot)] = tv3;
            }
        }
    }
    __syncthreads();

    // ---- Phase 2: 4-mat projection GEMM, A from LDS (unchanged) ----
    const int w = t >> 6, lane = t & 63;
    const int ln16 = lane & 15, quad = lane >> 4;
    const int wr = w >> 1, wc = w & 1;
    const int m_base_l = wr * 64;                 // local row base
    const int n_base = wc * 64;
    const floatx4 z4 = {0.f, 0.f, 0.f, 0.f};

    const int m = blk * 128 + m_base_l + lane;
    const int i = m >> 8, jk = m & 255;
    __bf16* __restrict__ Cw = &Cs[w][0];

    #pragma unroll 1
    for (int mat = 0; mat < 4; ++mat) {
        const __bf16* __restrict__ wT = wTg + mat * 16384;

        floatx4 Cf[4][4];
        #pragma unroll
        for (int mt = 0; mt < 4; ++mt)
            #pragma unroll
            for (int nt = 0; nt < 4; ++nt) Cf[mt][nt] = z4;

        #pragma unroll
        for (int ks = 0; ks < 4; ++ks) {
            bf16x8 Af[4], Bf[4];
            #pragma unroll
            for (int mt = 0; mt < 4; ++mt)
                Af[mt] = *(const bf16x8*)&Als[(m_base_l + mt*16 + ln16) * 136 + ks*32 + quad*8];
            #pragma unroll
            for (int nt = 0; nt < 4; ++nt)
                Bf[nt] = *(const bf16x8*)&wT[(n_base + nt*16 + ln16) * 128 + ks*32 + quad*8];
            #pragma unroll
            for (int mt = 0; mt < 4; ++mt)
                #pragma unroll
                for (int nt = 0; nt < 4; ++nt)
                    Cf[mt][nt] = mfma16(Af[mt], Bf[nt], Cf[mt][nt]);
        }

        const float scl = (mat == 0) ? SCALE : 1.0f;
        #pragma unroll
        for (int mt = 0; mt < 4; ++mt)
            #pragma unroll
            for (int nt = 0; nt < 4; ++nt)
                #pragma unroll
                for (int r = 0; r < 4; ++r)
                    Cw[(mt*16 + quad*4 + r) * 72 + nt*16 + ln16] =
                        (__bf16)(Cf[mt][nt][r] * scl);

        __bf16* __restrict__ dst = (mat == 0) ? qbuf : (mat == 1) ? kbuf
                                 : (mat == 2) ? vbuf : gbuf;
        #pragma unroll
        for (int hf = 0; hf < 2; ++hf) {
            const int hh = wc * 2 + hf;
            __bf16* __restrict__ drow = dst + (((size_t)i*4 + hh)*256 + jk)*32;
            #pragma unroll
            for (int u = 0; u < 4; ++u)
                *(bf16x8*)&drow[u*8] = *(const bf16x8*)&Cw[lane*72 + hf*32 + u*8];
        }
    }
}

// ---------------------------------------------------------------------------
// K3: MFMA attention — EXACT R10 kernel (best attn: 65.4 us, zero spill).
// attn is at a structural floor for this algorithm family: residency
// 2/3/4 blocks identical (R8/9/10), 8-wave chain-split worse (R12),
// register-paid DS cuts spill past the ~128-VGPR ceiling (R11), swapped-QK
// restructure worse (R5-R7). Parked.
// Ks XOR-swizzled; Pw 32-key chunks; bias folded into MFMA C (R6);
// K LDS-staged (R3); launch bounds (256,2) (R5). Rule #20 throughout.
// ---------------------------------------------------------------------------
__global__ __launch_bounds__(256, 2) void attn_kernel(
    const float* __restrict__ tbp, const float* __restrict__ mask,
    const float* __restrict__ bg,
    const __bf16* __restrict__ qbuf, const __bf16* __restrict__ kbuf,
    const __bf16* __restrict__ vbuf, const __bf16* __restrict__ gbuf,
    _Float16* __restrict__ ogh)
{
    const int bid = blockIdx.x;
    const int i = bid & 255, h = bid >> 8;
    const int t = threadIdx.x, w = t >> 6, lane = t & 63;
    const int ln16 = lane & 15, quad = lane >> 4;

    __shared__ __align__(16) __bf16 Ks[256 * 32];      // 16384 B (swizzled)
    __shared__ __align__(16) __bf16 VT[32 * 264];      // 16896 B
    __shared__ __align__(16) __bf16 Pw[4][16 * 40];    //  5120 B
    __shared__ float mb[256];                          //  1024 B

    const size_t hb = (size_t)i * 4 + h;
    const __bf16* __restrict__ qb = qbuf + hb * 8192;
    const __bf16* __restrict__ kb = kbuf + hb * 8192;
    const __bf16* __restrict__ vb = vbuf + hb * 8192;
    const __bf16* __restrict__ gb = gbuf + hb * 8192;

    // K staging: swizzled 16B-block placement
    {
        const int xt = (t & 3) ^ ((t >> 2) & 3);
        #pragma unroll
        for (int u = 0; u < 4; ++u)
            *(bf16x8*)&Ks[t * 32 + ((u ^ xt) * 8)] = *(const bf16x8*)&kb[t * 32 + u * 8];
    }
    #pragma unroll
    for (int u = 0; u < 4; ++u) {
        const bf16x8 vv = *(const bf16x8*)&vb[t * 32 + u * 8];
        #pragma unroll
        for (int e = 0; e < 8; ++e) VT[(u*8 + e) * 264 + t] = vv[e];
    }
    mb[t] = INFB * (mask[(size_t)t * N + i] - 1.0f);
    __syncthreads();

    const float bg0 = bg[h*32 + ln16], bg1 = bg[h*32 + 16 + ln16];

    float mbv[16];
    #pragma unroll
    for (int kt = 0; kt < 16; ++kt) mbv[kt] = mb[kt*16 + ln16];

    // per-lane constant swizzled K-block offset
    const int kq = ((quad ^ ((ln16 & 3) ^ ((ln16 >> 2) & 3))) * 8);

    __bf16* __restrict__ Pww = &Pw[w][0];
    const floatx4 z4 = {0.f, 0.f, 0.f, 0.f};
    _Float16* __restrict__ ogb = ogh + ((size_t)h * 256 + i) * 8192;

    #pragma unroll 1
    for (int jt = 0; jt < 4; ++jt) {
        const int jrow0 = w*64 + jt*16;
        // per-lane contiguous 256B slab of pre-permuted tri-bias
        const float* __restrict__ tbl =
            tbp + ((size_t)((h*16 + (w*4 + jt))*64 + lane) << 6);
        const bf16x8 Qf = *(const bf16x8*)&qb[(jrow0 + ln16)*32 + quad*8];

        // ---- scores with bias folded into the MFMA C-operand ----
        floatx4 S[16];
        #pragma unroll
        for (int kt = 0; kt < 16; ++kt) {
            const float4 tb4 = *(const float4*)&tbl[kt*4];
            const float mbk = mbv[kt];
            floatx4 c;
            c[0] = mbk + tb4.x;
            c[1] = mbk + tb4.y;
            c[2] = mbk + tb4.z;
            c[3] = mbk + tb4.w;
            const bf16x8 Kf = *(const bf16x8*)&Ks[(kt*16 + ln16)*32 + kq];
            S[kt] = mfma16(Qf, Kf, c);
        }

        // ---- full-row softmax (16-lane shfl reduce) ----
        float mrow[4], l[4];
        #pragma unroll
        for (int r = 0; r < 4; ++r) {
            float mx = S[0][r];
            #pragma unroll
            for (int kt = 1; kt < 16; ++kt) mx = fmaxf(mx, S[kt][r]);
            #pragma unroll
            for (int off = 1; off < 16; off <<= 1) mx = fmaxf(mx, __shfl_xor(mx, off));
            mrow[r] = mx; l[r] = 0.f;
        }
        #pragma unroll
        for (int kt = 0; kt < 16; ++kt)
            #pragma unroll
            for (int r = 0; r < 4; ++r) {
                const float p = __expf(S[kt][r] - mrow[r]);
                S[kt][r] = p; l[r] += p;
            }
        #pragma unroll
        for (int r = 0; r < 4; ++r)
            #pragma unroll
            for (int off = 1; off < 16; off <<= 1) l[r] += __shfl_xor(l[r], off);

        // ---- PV in 8 key-chunks of 32: P-chunk -> LDS, 1 MFMA pair each ----
        floatx4 O0 = z4, O1 = z4;
        #pragma unroll
        for (int ch = 0; ch < 8; ++ch) {
            #pragma unroll
            for (int kk = 0; kk < 2; ++kk) {
                const int kt = ch*2 + kk;
                #pragma unroll
                for (int r = 0; r < 4; ++r)
                    Pww[(quad*4 + r)*40 + kk*16 + ln16] = (__bf16)S[kt][r];
            }
            const bf16x8 Af = *(const bf16x8*)&Pww[ln16*40 + quad*8];
            const bf16x8 V0 = *(const bf16x8*)&VT[ln16*264 + ch*32 + quad*8];
            const bf16x8 V1 = *(const bf16x8*)&VT[(16 + ln16)*264 + ch*32 + quad*8];
            O0 = mfma16(Af, V0, O0);
            O1 = mfma16(Af, V1, O1);
        }

        // ---- normalize+gate -> fp16 repack in wave-private LDS ----
        _Float16* Po = (_Float16*)Pww;
        #pragma unroll
        for (int r = 0; r < 4; ++r) {
            const float inv = 1.0f / l[r];
            const int jrow = jrow0 + quad*4 + r;
            const float g0 = (float)gb[jrow*32 + ln16];
            const float g1 = (float)gb[jrow*32 + 16 + ln16];
            const float gate0 = 1.0f / (1.0f + __expf(-(g0 + bg0)));
            const float gate1 = 1.0f / (1.0f + __expf(-(g1 + bg1)));
            Po[(quad*4 + r)*40 + ln16]      = (_Float16)(O0[r] * inv * gate0);
            Po[(quad*4 + r)*40 + 16 + ln16] = (_Float16)(O1[r] * inv * gate1);
        }
        // contiguous 1KB-per-wave store (in-order DS pipe, wave-private)
        {
            const int rr = lane >> 2, cc = lane & 3;
            const halfx8 ov = *(const halfx8*)&Po[rr*40 + cc*8];
            *(halfx8*)&ogb[(size_t)(jrow0 + rr)*32 + cc*8] = ov;
        }
    }
}

// ---------------------------------------------------------------------------
// K4: output projection as f16 MFMA GEMM: out[(j*256+i)*128 + c] =
// sum_k og[(i*256+j), k] * woh[c, k] + bo[c], k = h*32+d over 4 head-slices.
// No LDS; A from og fp16 (coalesced), B from woh (L2-resident).
// ---------------------------------------------------------------------------
__global__ __launch_bounds__(256, 4) void outproj_kernel(
    const _Float16* __restrict__ og, const _Float16* __restrict__ woh,
    const float* __restrict__ bo, float* __restrict__ out)
{
    const int t = threadIdx.x, w = t >> 6, lane = t & 63;
    const int ln16 = lane & 15, quad = lane >> 4;
    const int wr = w >> 1, wc = w & 1;
    const int m_base = blockIdx.x * 128 + wr * 64;
    const int n_base = wc * 64;

    floatx4 Cf[4][4];
    const floatx4 z4 = {0.f, 0.f, 0.f, 0.f};
    #pragma unroll
    for (int mt = 0; mt < 4; ++mt)
        #pragma unroll
        for (int nt = 0; nt < 4; ++nt) Cf[mt][nt] = z4;

    #pragma unroll
    for (int ks = 0; ks < 4; ++ks) {   // ks = head
        halfx8 Af[4], Bf[4];
        #pragma unroll
        for (int mt = 0; mt < 4; ++mt)
            Af[mt] = *(const halfx8*)&og[(size_t)ks*2097152 + (size_t)(m_base + mt*16 + ln16)*32 + quad*8];
        #pragma unroll
        for (int nt = 0; nt < 4; ++nt)
            Bf[nt] = *(const halfx8*)&woh[(n_base + nt*16 + ln16)*128 + ks*32 + quad*8];
        #pragma unroll
        for (int mt = 0; mt < 4; ++mt)
            #pragma unroll
            for (int nt = 0; nt < 4; ++nt)
                Cf[mt][nt] = mfma16h(Af[mt], Bf[nt], Cf[mt][nt]);
    }

    float bov[4];
    #pragma unroll
    for (int nt = 0; nt < 4; ++nt) bov[nt] = bo[n_base + nt*16 + ln16];

    #pragma unroll
    for (int mt = 0; mt < 4; ++mt)
        #pragma unroll
        for (int r = 0; r < 4; ++r) {
            const int m = m_base + mt*16 + quad*4 + r;
            const size_t orow = (size_t)(m & 255) * 256 + (m >> 8);  // (j,i)
            #pragma unroll
            for (int nt = 0; nt < 4; ++nt)
                out[orow*128 + n_base + nt*16 + ln16] = Cf[mt][nt][r] + bov[nt];
        }
}

// ---------------------------------------------------------------------------
extern "C" void kernel_launch(void* const* d_in, const int* in_sizes, int n_in,
                              void* d_out, int out_size, void* d_ws, size_t ws_size,
                              hipStream_t stream) {
    const float* x     = (const float*)d_in[0];
    const float* mask  = (const float*)d_in[1];
    const float* lnw   = (const float*)d_in[2];
    const float* lnb   = (const float*)d_in[3];
    const float* wbias = (const float*)d_in[4];
    const float* wq    = (const float*)d_in[5];
    const float* wk    = (const float*)d_in[6];
    const float* wv    = (const float*)d_in[7];
    const float* wg    = (const float*)d_in[8];
    const float* bg    = (const float*)d_in[9];
    const float* wo    = (const float*)d_in[10];
    const float* bo    = (const float*)d_in[11];
    float* out = (float*)d_out;

    char* wsb = (char*)d_ws;
    float*     tbp  = (float*)    (wsb + 16777216);   //  1.05 MB (permuted)
    __bf16*    wTg  = (__bf16*)   (wsb + 17825792);   //  0.13 MB
    _Float16*  woh  = (_Float16*) (wsb + 17956864);   //  0.03 MB
    __bf16*    qbuf = (__bf16*)   (wsb + 17989632);   // 16.78 MB
    __bf16*    kbuf = (__bf16*)   (wsb + 34766848);   // 16.78 MB
    __bf16*    vbuf = (__bf16*)   (wsb + 51544064);   // 16.78 MB
    __bf16*    gbuf = (__bf16*)   (wsb + 68321280);   // 16.78 MB
    _Float16*  ogh  = (_Float16*) (wsb + 85098496);   // 16.78 MB

    wt_kernel<<<40, 256, 0, stream>>>(wq, wk, wv, wg, wo, wTg, woh);
    lnproj_kernel<<<512, 256, 0, stream>>>(x, lnw, lnb, wbias, wTg, tbp,
                                           qbuf, kbuf, vbuf, gbuf);
    attn_kernel<<<1024, 256, 0, stream>>>(tbp, mask, bg, qbuf, kbuf, vbuf, gbuf, ogh);
    outproj_kernel<<<512, 256, 0, stream>>>(ogh, woh, bo, out);
}